// Round 5
// baseline (756.861 us; speedup 1.0000x reference)
//
#include <hip/hip_runtime.h>
#include <math.h>

#define E 1024
#define H 16
#define HD 64
#define B 32
#define S 2048
#define PSPLIT 32
#define PCHUNK (S / PSPLIT)  // 64  (atomic fallback path)
#define PS2 32
#define PT2 (S / PS2)        // 64  (partials path)

// ---------------------------------------------------------------- q = Wq @ seed + bq
__global__ __launch_bounds__(256) void qproj_kernel(const float* __restrict__ W,
                                                    const float* __restrict__ bqkv,
                                                    const float* __restrict__ seed,
                                                    float* __restrict__ q) {
    int gw = (blockIdx.x * 256 + threadIdx.x) >> 6;  // e index
    int lane = threadIdx.x & 63;
    if (gw >= E) return;
    const float4* row = (const float4*)(W + (size_t)gw * E);
    const float4* sd = (const float4*)seed;
    float acc = 0.f;
#pragma unroll
    for (int k = 0; k < 4; ++k) {
        float4 w4 = row[k * 64 + lane];
        float4 s4 = sd[k * 64 + lane];
        acc = fmaf(w4.x, s4.x, acc); acc = fmaf(w4.y, s4.y, acc);
        acc = fmaf(w4.z, s4.z, acc); acc = fmaf(w4.w, s4.w, acc);
    }
#pragma unroll
    for (int off = 32; off > 0; off >>= 1) acc += __shfl_down(acc, off, 64);
    if (lane == 0) q[gw] = acc + bqkv[gw];
}

// ---------------------------------------------------------------- u[h][e] = scale * sum_d q[h*64+d] * Wk[h*64+d][e]
__global__ __launch_bounds__(256) void uproj_kernel(const float* __restrict__ W,
                                                    const float* __restrict__ q,
                                                    float* __restrict__ u) {
    int h = blockIdx.y;
    int e = blockIdx.x * 256 + threadIdx.x;
    __shared__ float qs[HD];
    if (threadIdx.x < HD) qs[threadIdx.x] = q[h * HD + threadIdx.x];
    __syncthreads();
    const float* Wk = W + ((size_t)(E + h * HD)) * E + e;
    float acc = 0.f;
#pragma unroll 8
    for (int d = 0; d < HD; ++d) acc = fmaf(qs[d], Wk[(size_t)d * E], acc);
    u[h * E + e] = acc * 0.125f;  // 1/sqrt(64)
}

// ---------------------------------------------------------------- scores[b][h][s] = u[h] . x[b][s]
// v4: v3 + explicit register double-buffer prefetch of the next k-step's x loads.
__global__ __launch_bounds__(512, 4) void scores_kernel(const float* __restrict__ x,
                                                        const int* __restrict__ mask,
                                                        const float* __restrict__ u,
                                                        float* __restrict__ scores) {
    __shared__ float4 uT[4096];  // [e4][h^(e4&7)] -> 64 KB
    for (int idx = threadIdx.x; idx < 4096; idx += 512) {
        int h = idx >> 8, e4 = idx & 255;
        uT[e4 * 16 + (h ^ (e4 & 7))] = ((const float4*)(u + (size_t)h * E))[e4];
    }
    __syncthreads();

    int lane = threadIdx.x & 63;
    int wid = threadIdx.x >> 6;
    int m = lane & 15, g = lane >> 4;
    int gwave = blockIdx.x * 8 + wid;   // 0..4095
    int tb = gwave * 16;
    int tok0 = tb + g * 4;              // my 4 tokens
    int b0 = tok0 >> 11;
    int s0 = tok0 & (S - 1);

    int mk[4];
#pragma unroll
    for (int t = 0; t < 4; ++t) mk[t] = mask[(size_t)b0 * S + s0 + t];

    const float* xb = x + (size_t)tok0 * E + m * 4;

    float acc[64];
#pragma unroll
    for (int i = 0; i < 64; ++i) acc[i] = 0.f;

    float4 xv[4], nx[4];
#pragma unroll
    for (int t = 0; t < 4; ++t) {
        xv[t] = make_float4(0.f, 0.f, 0.f, 0.f);
        if (mk[t]) xv[t] = *(const float4*)(xb + (size_t)t * E);
    }

#pragma unroll
    for (int k = 0; k < 16; ++k) {
        if (k < 15) {
#pragma unroll
            for (int t = 0; t < 4; ++t) {
                nx[t] = make_float4(0.f, 0.f, 0.f, 0.f);
                if (mk[t]) nx[t] = *(const float4*)(xb + (size_t)t * E + (k + 1) * 64);
            }
        }
        const float4* uk = uT + k * 256 + m * 16;
        int sw = m & 7;
#pragma unroll
        for (int h = 0; h < 16; ++h) {
            float4 uv = uk[h ^ sw];
#pragma unroll
            for (int t = 0; t < 4; ++t) {
                acc[t * 16 + h] = fmaf(xv[t].x, uv.x, acc[t * 16 + h]);
                acc[t * 16 + h] = fmaf(xv[t].y, uv.y, acc[t * 16 + h]);
                acc[t * 16 + h] = fmaf(xv[t].z, uv.z, acc[t * 16 + h]);
                acc[t * 16 + h] = fmaf(xv[t].w, uv.w, acc[t * 16 + h]);
            }
        }
#pragma unroll
        for (int t = 0; t < 4; ++t) xv[t] = nx[t];
    }

    // packing butterfly over the 16 m-lanes: 64 -> 32 -> 16 -> 8 -> 4 values
    float v32[32];
    {
        bool up = (lane & 8) != 0;
#pragma unroll
        for (int i = 0; i < 32; ++i) {
            float lo = acc[i], hi = acc[32 + i];
            float send = up ? lo : hi, keep = up ? hi : lo;
            v32[i] = keep + __shfl_xor(send, 8, 64);
        }
    }
    float v16[16];
    {
        bool up = (lane & 4) != 0;
#pragma unroll
        for (int i = 0; i < 16; ++i) {
            float lo = v32[i], hi = v32[16 + i];
            float send = up ? lo : hi, keep = up ? hi : lo;
            v16[i] = keep + __shfl_xor(send, 4, 64);
        }
    }
    float v8a[8];
    {
        bool up = (lane & 2) != 0;
#pragma unroll
        for (int i = 0; i < 8; ++i) {
            float lo = v16[i], hi = v16[8 + i];
            float send = up ? lo : hi, keep = up ? hi : lo;
            v8a[i] = keep + __shfl_xor(send, 2, 64);
        }
    }
    float v4a[4];
    {
        bool up = (lane & 1) != 0;
#pragma unroll
        for (int i = 0; i < 4; ++i) {
            float lo = v8a[i], hi = v8a[4 + i];
            float send = up ? lo : hi, keep = up ? hi : lo;
            v4a[i] = keep + __shfl_xor(send, 1, 64);
        }
    }
    int t = m >> 2;
    int h0 = (m & 3) * 4;
    int tok = tok0 + t;
    int bb = tok >> 11, s = tok & (S - 1);
#pragma unroll
    for (int j = 0; j < 4; ++j)
        scores[((size_t)(bb * H + h0 + j)) * S + s] = v4a[j];
}

// ---------------------------------------------------------------- masked softmax over S per (b,h)
__global__ __launch_bounds__(256) void softmax_kernel(float* __restrict__ scores,
                                                      const int* __restrict__ mask) {
    int bh = blockIdx.x;
    int b = bh >> 4;
    float* row = scores + (size_t)bh * S;
    const int* mrow = mask + (size_t)b * S;
    int t = threadIdx.x, lane = t & 63, wid = t >> 6;
    float vals[8];
    float mx = -1e30f;
#pragma unroll
    for (int i = 0; i < 8; ++i) {
        int s = i * 256 + t;
        float v = row[s];
        if (mrow[s] == 0) v = -1e30f;
        vals[i] = v;
        mx = fmaxf(mx, v);
    }
    __shared__ float redm[4], reds[4];
#pragma unroll
    for (int off = 32; off > 0; off >>= 1) mx = fmaxf(mx, __shfl_down(mx, off, 64));
    if (lane == 0) redm[wid] = mx;
    __syncthreads();
    mx = fmaxf(fmaxf(redm[0], redm[1]), fmaxf(redm[2], redm[3]));
    float sum = 0.f;
#pragma unroll
    for (int i = 0; i < 8; ++i) {
        float p = __expf(vals[i] - mx);
        vals[i] = p;
        sum += p;
    }
#pragma unroll
    for (int off = 32; off > 0; off >>= 1) sum += __shfl_down(sum, off, 64);
    if (lane == 0) reds[wid] = sum;
    __syncthreads();
    sum = reds[0] + reds[1] + reds[2] + reds[3];
    float inv = 1.f / sum;
#pragma unroll
    for (int i = 0; i < 8; ++i) row[i * 256 + t] = vals[i] * inv;
}

// ---------------------------------------------------------------- pool v3: partials, no atomics
// grid (PS2=32, B) = 1024 blocks (4/CU), 256 thr x float4 e-slice, mask-skip,
// attn staged [s][h] (coalesced stage, broadcast reads), plain partial stores.
__global__ __launch_bounds__(256, 4) void pool3_kernel(const float* __restrict__ x,
                                                       const float* __restrict__ attn,
                                                       const int* __restrict__ mask,
                                                       float* __restrict__ part) {
    int sp = blockIdx.x, b = blockIdx.y;
    int t = threadIdx.x;  // 0..255
    __shared__ float at[PT2 * 16];  // [s][h], 4 KB
    __shared__ int mk[PT2];
    for (int i = t; i < PT2 * 16; i += 256) {
        int s = i & (PT2 - 1), h = i >> 6;
        at[s * 16 + h] = attn[((size_t)(b * H + h)) * S + sp * PT2 + s];
    }
    if (t < PT2) mk[t] = mask[(size_t)b * S + sp * PT2 + t];
    __syncthreads();
    const float4* xr = (const float4*)(x + ((size_t)b * S + sp * PT2) * E);
    float4 acc[H];
#pragma unroll
    for (int h = 0; h < H; ++h) acc[h] = make_float4(0.f, 0.f, 0.f, 0.f);
    for (int s = 0; s < PT2; ++s) {
        if (mk[s] == 0) continue;
        float4 xv = xr[(size_t)s * (E / 4) + t];
        const float4* ah = (const float4*)(at + s * 16);
        float4 a0 = ah[0], a1 = ah[1], a2 = ah[2], a3 = ah[3];
        acc[0].x = fmaf(a0.x, xv.x, acc[0].x);  acc[0].y = fmaf(a0.x, xv.y, acc[0].y);
        acc[0].z = fmaf(a0.x, xv.z, acc[0].z);  acc[0].w = fmaf(a0.x, xv.w, acc[0].w);
        acc[1].x = fmaf(a0.y, xv.x, acc[1].x);  acc[1].y = fmaf(a0.y, xv.y, acc[1].y);
        acc[1].z = fmaf(a0.y, xv.z, acc[1].z);  acc[1].w = fmaf(a0.y, xv.w, acc[1].w);
        acc[2].x = fmaf(a0.z, xv.x, acc[2].x);  acc[2].y = fmaf(a0.z, xv.y, acc[2].y);
        acc[2].z = fmaf(a0.z, xv.z, acc[2].z);  acc[2].w = fmaf(a0.z, xv.w, acc[2].w);
        acc[3].x = fmaf(a0.w, xv.x, acc[3].x);  acc[3].y = fmaf(a0.w, xv.y, acc[3].y);
        acc[3].z = fmaf(a0.w, xv.z, acc[3].z);  acc[3].w = fmaf(a0.w, xv.w, acc[3].w);
        acc[4].x = fmaf(a1.x, xv.x, acc[4].x);  acc[4].y = fmaf(a1.x, xv.y, acc[4].y);
        acc[4].z = fmaf(a1.x, xv.z, acc[4].z);  acc[4].w = fmaf(a1.x, xv.w, acc[4].w);
        acc[5].x = fmaf(a1.y, xv.x, acc[5].x);  acc[5].y = fmaf(a1.y, xv.y, acc[5].y);
        acc[5].z = fmaf(a1.y, xv.z, acc[5].z);  acc[5].w = fmaf(a1.y, xv.w, acc[5].w);
        acc[6].x = fmaf(a1.z, xv.x, acc[6].x);  acc[6].y = fmaf(a1.z, xv.y, acc[6].y);
        acc[6].z = fmaf(a1.z, xv.z, acc[6].z);  acc[6].w = fmaf(a1.z, xv.w, acc[6].w);
        acc[7].x = fmaf(a1.w, xv.x, acc[7].x);  acc[7].y = fmaf(a1.w, xv.y, acc[7].y);
        acc[7].z = fmaf(a1.w, xv.z, acc[7].z);  acc[7].w = fmaf(a1.w, xv.w, acc[7].w);
        acc[8].x = fmaf(a2.x, xv.x, acc[8].x);  acc[8].y = fmaf(a2.x, xv.y, acc[8].y);
        acc[8].z = fmaf(a2.x, xv.z, acc[8].z);  acc[8].w = fmaf(a2.x, xv.w, acc[8].w);
        acc[9].x = fmaf(a2.y, xv.x, acc[9].x);  acc[9].y = fmaf(a2.y, xv.y, acc[9].y);
        acc[9].z = fmaf(a2.y, xv.z, acc[9].z);  acc[9].w = fmaf(a2.y, xv.w, acc[9].w);
        acc[10].x = fmaf(a2.z, xv.x, acc[10].x); acc[10].y = fmaf(a2.z, xv.y, acc[10].y);
        acc[10].z = fmaf(a2.z, xv.z, acc[10].z); acc[10].w = fmaf(a2.z, xv.w, acc[10].w);
        acc[11].x = fmaf(a2.w, xv.x, acc[11].x); acc[11].y = fmaf(a2.w, xv.y, acc[11].y);
        acc[11].z = fmaf(a2.w, xv.z, acc[11].z); acc[11].w = fmaf(a2.w, xv.w, acc[11].w);
        acc[12].x = fmaf(a3.x, xv.x, acc[12].x); acc[12].y = fmaf(a3.x, xv.y, acc[12].y);
        acc[12].z = fmaf(a3.x, xv.z, acc[12].z); acc[12].w = fmaf(a3.x, xv.w, acc[12].w);
        acc[13].x = fmaf(a3.y, xv.x, acc[13].x); acc[13].y = fmaf(a3.y, xv.y, acc[13].y);
        acc[13].z = fmaf(a3.y, xv.z, acc[13].z); acc[13].w = fmaf(a3.y, xv.w, acc[13].w);
        acc[14].x = fmaf(a3.z, xv.x, acc[14].x); acc[14].y = fmaf(a3.z, xv.y, acc[14].y);
        acc[14].z = fmaf(a3.z, xv.z, acc[14].z); acc[14].w = fmaf(a3.z, xv.w, acc[14].w);
        acc[15].x = fmaf(a3.w, xv.x, acc[15].x); acc[15].y = fmaf(a3.w, xv.y, acc[15].y);
        acc[15].z = fmaf(a3.w, xv.z, acc[15].z); acc[15].w = fmaf(a3.w, xv.w, acc[15].w);
    }
    float4* pp = (float4*)(part + ((size_t)(sp * B + b)) * (H * E));
#pragma unroll
    for (int h = 0; h < H; ++h) pp[h * (E / 4) + t] = acc[h];
}

// ---------------------------------------------------------------- xbar = sum_sp part[sp]
__global__ __launch_bounds__(256) void reduce32_kernel(const float* __restrict__ part,
                                                       float* __restrict__ xbar) {
    size_t i = (size_t)blockIdx.x * 256 + threadIdx.x;  // float4 index, B*H*E/4 total
    const float4* p = (const float4*)part;
    float4 s = p[i];
#pragma unroll
    for (int sp = 1; sp < PS2; ++sp) {
        float4 v = p[(size_t)sp * (B * H * E / 4) + i];
        s.x += v.x; s.y += v.y; s.z += v.z; s.w += v.w;
    }
    ((float4*)xbar)[i] = s;
}

// ---------------------------------------------------------------- pool (atomic fallback)
__global__ __launch_bounds__(256) void pool_kernel(const float* __restrict__ x,
                                                   const float* __restrict__ attn,
                                                   const int* __restrict__ mask,
                                                   float* __restrict__ xbar) {
    int sp = blockIdx.x, b = blockIdx.y;
    int t = threadIdx.x;
    __shared__ float at[H][PCHUNK];
    __shared__ int mk[PCHUNK];
    for (int i = t; i < H * PCHUNK; i += 256) {
        int h = i / PCHUNK, s = i % PCHUNK;
        at[h][s] = attn[((size_t)(b * H + h)) * S + sp * PCHUNK + s];
    }
    for (int i = t; i < PCHUNK; i += 256) mk[i] = mask[(size_t)b * S + sp * PCHUNK + i];
    __syncthreads();
    const float4* xr = (const float4*)(x + ((size_t)(b * S) + sp * PCHUNK) * E);
    float4 acc[H];
#pragma unroll
    for (int h = 0; h < H; ++h) acc[h] = make_float4(0.f, 0.f, 0.f, 0.f);
    for (int s = 0; s < PCHUNK; ++s) {
        if (mk[s] == 0) continue;
        float4 xv = xr[(size_t)s * (E / 4) + t];
#pragma unroll
        for (int h = 0; h < H; ++h) {
            float a = at[h][s];
            acc[h].x = fmaf(a, xv.x, acc[h].x);
            acc[h].y = fmaf(a, xv.y, acc[h].y);
            acc[h].z = fmaf(a, xv.z, acc[h].z);
            acc[h].w = fmaf(a, xv.w, acc[h].w);
        }
    }
    float* xb = xbar + (size_t)b * H * E + t * 4;
#pragma unroll
    for (int h = 0; h < H; ++h) {
        atomicAdd(&xb[h * E + 0], acc[h].x);
        atomicAdd(&xb[h * E + 1], acc[h].y);
        atomicAdd(&xb[h * E + 2], acc[h].z);
        atomicAdd(&xb[h * E + 3], acc[h].w);
    }
}

// ---------------------------------------------------------------- ctx[b][c] = bv[c] + Wv[c] . xbar[b][h(c)]
__global__ __launch_bounds__(256) void ctx_kernel(const float* __restrict__ W,
                                                  const float* __restrict__ bqkv,
                                                  const float* __restrict__ xbar,
                                                  float* __restrict__ ctx) {
    int cb = blockIdx.x, b = blockIdx.y, t = threadIdx.x;
    int c = cb * 256 + t;
    int h0 = cb * 4;
    __shared__ float xls[4 * E];  // 16 KB
    const float4* xbp = (const float4*)(xbar + ((size_t)b * H + h0) * E);
    for (int i = t; i < 4 * E / 4; i += 256) ((float4*)xls)[i] = xbp[i];
    __syncthreads();
    int h = c >> 6;
    const float4* wr = (const float4*)(W + ((size_t)(2 * E + c)) * E);
    const float4* xl = (const float4*)(xls + (h - h0) * E);
    float acc = bqkv[2 * E + c];
#pragma unroll 4
    for (int e4 = 0; e4 < E / 4; ++e4) {
        float4 w = wr[e4], xv = xl[e4];
        acc = fmaf(w.x, xv.x, acc); acc = fmaf(w.y, xv.y, acc);
        acc = fmaf(w.z, xv.z, acc); acc = fmaf(w.w, xv.w, acc);
    }
    ctx[(size_t)b * E + c] = acc;
}

// ---------------------------------------------------------------- out[b][o] = ob[o] + Wo[o] . ctx[b]
__global__ __launch_bounds__(256) void outproj_kernel(const float* __restrict__ Wo,
                                                      const float* __restrict__ ob,
                                                      const float* __restrict__ ctx,
                                                      float* __restrict__ outpre) {
    int obk = blockIdx.x, b = blockIdx.y, t = threadIdx.x;
    int o = obk * 256 + t;
    __shared__ float cl[E];  // 4 KB
    const float4* cp = (const float4*)(ctx + (size_t)b * E);
    for (int i = t; i < E / 4; i += 256) ((float4*)cl)[i] = cp[i];
    __syncthreads();
    const float4* wr = (const float4*)(Wo + (size_t)o * E);
    const float4* cl4 = (const float4*)cl;
    float acc = ob[o];
#pragma unroll 4
    for (int e4 = 0; e4 < E / 4; ++e4) {
        float4 w = wr[e4], cv = cl4[e4];
        acc = fmaf(w.x, cv.x, acc); acc = fmaf(w.y, cv.y, acc);
        acc = fmaf(w.z, cv.z, acc); acc = fmaf(w.w, cv.w, acc);
    }
    outpre[(size_t)b * E + o] = acc;
}

// ---------------------------------------------------------------- LayerNorm over E per b
__global__ __launch_bounds__(256) void ln_kernel(const float* __restrict__ outpre,
                                                 const float* __restrict__ g,
                                                 const float* __restrict__ bb,
                                                 float* __restrict__ out) {
    int b = blockIdx.x, t = threadIdx.x, lane = t & 63, wid = t >> 6;
    const float4* row = (const float4*)(outpre + (size_t)b * E);
    float4 v = row[t];
    float s = v.x + v.y + v.z + v.w;
    float sq = v.x * v.x + v.y * v.y + v.z * v.z + v.w * v.w;
    __shared__ float rs[4], rq[4];
#pragma unroll
    for (int off = 32; off > 0; off >>= 1) {
        s += __shfl_down(s, off, 64);
        sq += __shfl_down(sq, off, 64);
    }
    if (lane == 0) { rs[wid] = s; rq[wid] = sq; }
    __syncthreads();
    s = rs[0] + rs[1] + rs[2] + rs[3];
    sq = rq[0] + rq[1] + rq[2] + rq[3];
    float mean = s * (1.f / E);
    float var = sq * (1.f / E) - mean * mean;
    float inv = rsqrtf(var + 1e-5f);
    float4 gv = ((const float4*)g)[t];
    float4 bv = ((const float4*)bb)[t];
    float4 o;
    o.x = (v.x - mean) * inv * gv.x + bv.x;
    o.y = (v.y - mean) * inv * gv.y + bv.y;
    o.z = (v.z - mean) * inv * gv.z + bv.z;
    o.w = (v.w - mean) * inv * gv.w + bv.w;
    ((float4*)(out + (size_t)b * E))[t] = o;
}

extern "C" void kernel_launch(void* const* d_in, const int* in_sizes, int n_in,
                              void* d_out, int out_size, void* d_ws, size_t ws_size,
                              hipStream_t stream) {
    const float* x    = (const float*)d_in[0];
    const int*   mask = (const int*)d_in[1];
    const float* seed = (const float*)d_in[2];
    const float* W    = (const float*)d_in[3];  // (3E, E)
    const float* bqkv = (const float*)d_in[4];  // (3E,)
    const float* Wo   = (const float*)d_in[5];  // (E, E)
    const float* ob   = (const float*)d_in[6];  // (E,)
    const float* g    = (const float*)d_in[7];
    const float* lb   = (const float*)d_in[8];
    float* out = (float*)d_out;

    float* ws = (float*)d_ws;
    float* q      = ws;                          // 1024
    float* u      = q + E;                       // 16384
    float* scores = u + H * E;                   // B*H*S = 1,048,576

    qproj_kernel<<<256, 256, 0, stream>>>(W, bqkv, seed, q);
    uproj_kernel<<<dim3(E / 256, H), 256, 0, stream>>>(W, q, u);
    scores_kernel<<<512, 512, 0, stream>>>(x, mask, u, scores);
    softmax_kernel<<<B * H, 256, 0, stream>>>(scores, mask);

    size_t base = (size_t)E + H * E + (size_t)B * H * S;
    size_t needA = (base + (size_t)PS2 * B * H * E + (size_t)B * H * E + 2 * (size_t)B * E) * sizeof(float);

    float* xbar;
    float* ctx;
    float* outpre;
    if (ws_size >= needA) {
        // partials path (no atomics)
        float* part = scores + (size_t)B * H * S;        // PS2*B*H*E
        xbar   = part + (size_t)PS2 * B * H * E;         // B*H*E
        ctx    = xbar + (size_t)B * H * E;
        outpre = ctx + (size_t)B * E;
        pool3_kernel<<<dim3(PS2, B), 256, 0, stream>>>(x, scores, mask, part);
        reduce32_kernel<<<(B * H * E / 4) / 256, 256, 0, stream>>>(part, xbar);
    } else {
        // atomic fallback
        xbar   = scores + (size_t)B * H * S;
        ctx    = xbar + (size_t)B * H * E;
        outpre = ctx + (size_t)B * E;
        hipMemsetAsync(xbar, 0, (size_t)B * H * E * sizeof(float), stream);
        pool_kernel<<<dim3(PSPLIT, B), 256, 0, stream>>>(x, scores, mask, xbar);
    }

    ctx_kernel<<<dim3(E / 256, B), 256, 0, stream>>>(W, bqkv, xbar, ctx);
    outproj_kernel<<<dim3(E / 256, B), 256, 0, stream>>>(Wo, ob, ctx, outpre);
    ln_kernel<<<B, 256, 0, stream>>>(outpre, g, lb, out);
}

// Round 6
// 181.248 us; speedup vs baseline: 4.1758x; 4.1758x over previous
//
#include <hip/hip_runtime.h>
#include <math.h>

#define E 1024
#define H 16
#define HD 64
#define B 32
#define S 2048
#define PSPLIT 32
#define PCHUNK (S / PSPLIT)  // 64  (atomic fallback path)
#define PS2 32
#define PT2 (S / PS2)        // 64  (partials path)

// ---------------------------------------------------------------- q = Wq @ seed + bq
__global__ __launch_bounds__(256) void qproj_kernel(const float* __restrict__ W,
                                                    const float* __restrict__ bqkv,
                                                    const float* __restrict__ seed,
                                                    float* __restrict__ q) {
    int gw = (blockIdx.x * 256 + threadIdx.x) >> 6;  // e index
    int lane = threadIdx.x & 63;
    if (gw >= E) return;
    const float4* row = (const float4*)(W + (size_t)gw * E);
    const float4* sd = (const float4*)seed;
    float acc = 0.f;
#pragma unroll
    for (int k = 0; k < 4; ++k) {
        float4 w4 = row[k * 64 + lane];
        float4 s4 = sd[k * 64 + lane];
        acc = fmaf(w4.x, s4.x, acc); acc = fmaf(w4.y, s4.y, acc);
        acc = fmaf(w4.z, s4.z, acc); acc = fmaf(w4.w, s4.w, acc);
    }
#pragma unroll
    for (int off = 32; off > 0; off >>= 1) acc += __shfl_down(acc, off, 64);
    if (lane == 0) q[gw] = acc + bqkv[gw];
}

// ---------------------------------------------------------------- u[h][e] = scale * sum_d q[h*64+d] * Wk[h*64+d][e]
__global__ __launch_bounds__(256) void uproj_kernel(const float* __restrict__ W,
                                                    const float* __restrict__ q,
                                                    float* __restrict__ u) {
    int h = blockIdx.y;
    int e = blockIdx.x * 256 + threadIdx.x;
    __shared__ float qs[HD];
    if (threadIdx.x < HD) qs[threadIdx.x] = q[h * HD + threadIdx.x];
    __syncthreads();
    const float* Wk = W + ((size_t)(E + h * HD)) * E + e;
    float acc = 0.f;
#pragma unroll 8
    for (int d = 0; d < HD; ++d) acc = fmaf(qs[d], Wk[(size_t)d * E], acc);
    u[h * E + e] = acc * 0.125f;  // 1/sqrt(64)
}

// ---------------------------------------------------------------- scores[b][h][s] = u[h] . x[b][s]
// v3 (reverted from v4): NO register prefetch — the 128-VGPR budget at
// __launch_bounds__(512,4) is exactly full with acc[64]+xv[4]; adding a
// prefetch buffer spilled to scratch (R5: WRITE_SIZE 1.19 GB, 620 us).
__global__ __launch_bounds__(512, 4) void scores_kernel(const float* __restrict__ x,
                                                        const int* __restrict__ mask,
                                                        const float* __restrict__ u,
                                                        float* __restrict__ scores) {
    __shared__ float4 uT[4096];  // [e4][h^(e4&7)] -> 64 KB
    for (int idx = threadIdx.x; idx < 4096; idx += 512) {
        int h = idx >> 8, e4 = idx & 255;
        uT[e4 * 16 + (h ^ (e4 & 7))] = ((const float4*)(u + (size_t)h * E))[e4];
    }
    __syncthreads();

    int lane = threadIdx.x & 63;
    int wid = threadIdx.x >> 6;
    int m = lane & 15, g = lane >> 4;
    int gwave = blockIdx.x * 8 + wid;   // 0..4095
    int tb = gwave * 16;
    int tok0 = tb + g * 4;              // my 4 tokens
    int b0 = tok0 >> 11;
    int s0 = tok0 & (S - 1);

    int mk[4];
#pragma unroll
    for (int t = 0; t < 4; ++t) mk[t] = mask[(size_t)b0 * S + s0 + t];

    const float* xb = x + (size_t)tok0 * E + m * 4;

    float acc[64];
#pragma unroll
    for (int i = 0; i < 64; ++i) acc[i] = 0.f;

    for (int k = 0; k < 16; ++k) {
        float4 xv[4];
#pragma unroll
        for (int t = 0; t < 4; ++t) {
            xv[t] = make_float4(0.f, 0.f, 0.f, 0.f);
            if (mk[t]) xv[t] = *(const float4*)(xb + (size_t)t * E + k * 64);
        }
        const float4* uk = uT + k * 256 + m * 16;
        int sw = m & 7;
#pragma unroll
        for (int h = 0; h < 16; ++h) {
            float4 uv = uk[h ^ sw];
#pragma unroll
            for (int t = 0; t < 4; ++t) {
                acc[t * 16 + h] = fmaf(xv[t].x, uv.x, acc[t * 16 + h]);
                acc[t * 16 + h] = fmaf(xv[t].y, uv.y, acc[t * 16 + h]);
                acc[t * 16 + h] = fmaf(xv[t].z, uv.z, acc[t * 16 + h]);
                acc[t * 16 + h] = fmaf(xv[t].w, uv.w, acc[t * 16 + h]);
            }
        }
    }

    // packing butterfly over the 16 m-lanes: 64 -> 32 -> 16 -> 8 -> 4 values
    float v32[32];
    {
        bool up = (lane & 8) != 0;
#pragma unroll
        for (int i = 0; i < 32; ++i) {
            float lo = acc[i], hi = acc[32 + i];
            float send = up ? lo : hi, keep = up ? hi : lo;
            v32[i] = keep + __shfl_xor(send, 8, 64);
        }
    }
    float v16[16];
    {
        bool up = (lane & 4) != 0;
#pragma unroll
        for (int i = 0; i < 16; ++i) {
            float lo = v32[i], hi = v32[16 + i];
            float send = up ? lo : hi, keep = up ? hi : lo;
            v16[i] = keep + __shfl_xor(send, 4, 64);
        }
    }
    float v8a[8];
    {
        bool up = (lane & 2) != 0;
#pragma unroll
        for (int i = 0; i < 8; ++i) {
            float lo = v16[i], hi = v16[8 + i];
            float send = up ? lo : hi, keep = up ? hi : lo;
            v8a[i] = keep + __shfl_xor(send, 2, 64);
        }
    }
    float v4a[4];
    {
        bool up = (lane & 1) != 0;
#pragma unroll
        for (int i = 0; i < 4; ++i) {
            float lo = v8a[i], hi = v8a[4 + i];
            float send = up ? lo : hi, keep = up ? hi : lo;
            v4a[i] = keep + __shfl_xor(send, 1, 64);
        }
    }
    int t = m >> 2;
    int h0 = (m & 3) * 4;
    int tok = tok0 + t;
    int bb = tok >> 11, s = tok & (S - 1);
#pragma unroll
    for (int j = 0; j < 4; ++j)
        scores[((size_t)(bb * H + h0 + j)) * S + s] = v4a[j];
}

// ---------------------------------------------------------------- masked softmax over S per (b,h)
__global__ __launch_bounds__(256) void softmax_kernel(float* __restrict__ scores,
                                                      const int* __restrict__ mask) {
    int bh = blockIdx.x;
    int b = bh >> 4;
    float* row = scores + (size_t)bh * S;
    const int* mrow = mask + (size_t)b * S;
    int t = threadIdx.x, lane = t & 63, wid = t >> 6;
    float vals[8];
    float mx = -1e30f;
#pragma unroll
    for (int i = 0; i < 8; ++i) {
        int s = i * 256 + t;
        float v = row[s];
        if (mrow[s] == 0) v = -1e30f;
        vals[i] = v;
        mx = fmaxf(mx, v);
    }
    __shared__ float redm[4], reds[4];
#pragma unroll
    for (int off = 32; off > 0; off >>= 1) mx = fmaxf(mx, __shfl_down(mx, off, 64));
    if (lane == 0) redm[wid] = mx;
    __syncthreads();
    mx = fmaxf(fmaxf(redm[0], redm[1]), fmaxf(redm[2], redm[3]));
    float sum = 0.f;
#pragma unroll
    for (int i = 0; i < 8; ++i) {
        float p = __expf(vals[i] - mx);
        vals[i] = p;
        sum += p;
    }
#pragma unroll
    for (int off = 32; off > 0; off >>= 1) sum += __shfl_down(sum, off, 64);
    if (lane == 0) reds[wid] = sum;
    __syncthreads();
    sum = reds[0] + reds[1] + reds[2] + reds[3];
    float inv = 1.f / sum;
#pragma unroll
    for (int i = 0; i < 8; ++i) row[i * 256 + t] = vals[i] * inv;
}

// ---------------------------------------------------------------- pool v3: partials, no atomics
// grid (PS2=32, B) = 1024 blocks (4/CU), 256 thr x float4 e-slice, mask-skip,
// attn staged [s][h] (coalesced stage, broadcast reads), plain partial stores.
__global__ __launch_bounds__(256, 4) void pool3_kernel(const float* __restrict__ x,
                                                       const float* __restrict__ attn,
                                                       const int* __restrict__ mask,
                                                       float* __restrict__ part) {
    int sp = blockIdx.x, b = blockIdx.y;
    int t = threadIdx.x;  // 0..255
    __shared__ float at[PT2 * 16];  // [s][h], 4 KB
    __shared__ int mk[PT2];
    for (int i = t; i < PT2 * 16; i += 256) {
        int s = i & (PT2 - 1), h = i >> 6;
        at[s * 16 + h] = attn[((size_t)(b * H + h)) * S + sp * PT2 + s];
    }
    if (t < PT2) mk[t] = mask[(size_t)b * S + sp * PT2 + t];
    __syncthreads();
    const float4* xr = (const float4*)(x + ((size_t)b * S + sp * PT2) * E);
    float4 acc[H];
#pragma unroll
    for (int h = 0; h < H; ++h) acc[h] = make_float4(0.f, 0.f, 0.f, 0.f);
    for (int s = 0; s < PT2; ++s) {
        if (mk[s] == 0) continue;
        float4 xv = xr[(size_t)s * (E / 4) + t];
        const float4* ah = (const float4*)(at + s * 16);
        float4 a0 = ah[0], a1 = ah[1], a2 = ah[2], a3 = ah[3];
        acc[0].x = fmaf(a0.x, xv.x, acc[0].x);  acc[0].y = fmaf(a0.x, xv.y, acc[0].y);
        acc[0].z = fmaf(a0.x, xv.z, acc[0].z);  acc[0].w = fmaf(a0.x, xv.w, acc[0].w);
        acc[1].x = fmaf(a0.y, xv.x, acc[1].x);  acc[1].y = fmaf(a0.y, xv.y, acc[1].y);
        acc[1].z = fmaf(a0.y, xv.z, acc[1].z);  acc[1].w = fmaf(a0.y, xv.w, acc[1].w);
        acc[2].x = fmaf(a0.z, xv.x, acc[2].x);  acc[2].y = fmaf(a0.z, xv.y, acc[2].y);
        acc[2].z = fmaf(a0.z, xv.z, acc[2].z);  acc[2].w = fmaf(a0.z, xv.w, acc[2].w);
        acc[3].x = fmaf(a0.w, xv.x, acc[3].x);  acc[3].y = fmaf(a0.w, xv.y, acc[3].y);
        acc[3].z = fmaf(a0.w, xv.z, acc[3].z);  acc[3].w = fmaf(a0.w, xv.w, acc[3].w);
        acc[4].x = fmaf(a1.x, xv.x, acc[4].x);  acc[4].y = fmaf(a1.x, xv.y, acc[4].y);
        acc[4].z = fmaf(a1.x, xv.z, acc[4].z);  acc[4].w = fmaf(a1.x, xv.w, acc[4].w);
        acc[5].x = fmaf(a1.y, xv.x, acc[5].x);  acc[5].y = fmaf(a1.y, xv.y, acc[5].y);
        acc[5].z = fmaf(a1.y, xv.z, acc[5].z);  acc[5].w = fmaf(a1.y, xv.w, acc[5].w);
        acc[6].x = fmaf(a1.z, xv.x, acc[6].x);  acc[6].y = fmaf(a1.z, xv.y, acc[6].y);
        acc[6].z = fmaf(a1.z, xv.z, acc[6].z);  acc[6].w = fmaf(a1.z, xv.w, acc[6].w);
        acc[7].x = fmaf(a1.w, xv.x, acc[7].x);  acc[7].y = fmaf(a1.w, xv.y, acc[7].y);
        acc[7].z = fmaf(a1.w, xv.z, acc[7].z);  acc[7].w = fmaf(a1.w, xv.w, acc[7].w);
        acc[8].x = fmaf(a2.x, xv.x, acc[8].x);  acc[8].y = fmaf(a2.x, xv.y, acc[8].y);
        acc[8].z = fmaf(a2.x, xv.z, acc[8].z);  acc[8].w = fmaf(a2.x, xv.w, acc[8].w);
        acc[9].x = fmaf(a2.y, xv.x, acc[9].x);  acc[9].y = fmaf(a2.y, xv.y, acc[9].y);
        acc[9].z = fmaf(a2.y, xv.z, acc[9].z);  acc[9].w = fmaf(a2.y, xv.w, acc[9].w);
        acc[10].x = fmaf(a2.z, xv.x, acc[10].x); acc[10].y = fmaf(a2.z, xv.y, acc[10].y);
        acc[10].z = fmaf(a2.z, xv.z, acc[10].z); acc[10].w = fmaf(a2.z, xv.w, acc[10].w);
        acc[11].x = fmaf(a2.w, xv.x, acc[11].x); acc[11].y = fmaf(a2.w, xv.y, acc[11].y);
        acc[11].z = fmaf(a2.w, xv.z, acc[11].z); acc[11].w = fmaf(a2.w, xv.w, acc[11].w);
        acc[12].x = fmaf(a3.x, xv.x, acc[12].x); acc[12].y = fmaf(a3.x, xv.y, acc[12].y);
        acc[12].z = fmaf(a3.x, xv.z, acc[12].z); acc[12].w = fmaf(a3.x, xv.w, acc[12].w);
        acc[13].x = fmaf(a3.y, xv.x, acc[13].x); acc[13].y = fmaf(a3.y, xv.y, acc[13].y);
        acc[13].z = fmaf(a3.y, xv.z, acc[13].z); acc[13].w = fmaf(a3.y, xv.w, acc[13].w);
        acc[14].x = fmaf(a3.z, xv.x, acc[14].x); acc[14].y = fmaf(a3.z, xv.y, acc[14].y);
        acc[14].z = fmaf(a3.z, xv.z, acc[14].z); acc[14].w = fmaf(a3.z, xv.w, acc[14].w);
        acc[15].x = fmaf(a3.w, xv.x, acc[15].x); acc[15].y = fmaf(a3.w, xv.y, acc[15].y);
        acc[15].z = fmaf(a3.w, xv.z, acc[15].z); acc[15].w = fmaf(a3.w, xv.w, acc[15].w);
    }
    float4* pp = (float4*)(part + ((size_t)(sp * B + b)) * (H * E));
#pragma unroll
    for (int h = 0; h < H; ++h) pp[h * (E / 4) + t] = acc[h];
}

// ---------------------------------------------------------------- xbar = sum_sp part[sp]
__global__ __launch_bounds__(256) void reduce32_kernel(const float* __restrict__ part,
                                                       float* __restrict__ xbar) {
    size_t i = (size_t)blockIdx.x * 256 + threadIdx.x;  // float4 index, B*H*E/4 total
    const float4* p = (const float4*)part;
    float4 s = p[i];
#pragma unroll
    for (int sp = 1; sp < PS2; ++sp) {
        float4 v = p[(size_t)sp * (B * H * E / 4) + i];
        s.x += v.x; s.y += v.y; s.z += v.z; s.w += v.w;
    }
    ((float4*)xbar)[i] = s;
}

// ---------------------------------------------------------------- pool (atomic fallback)
__global__ __launch_bounds__(256) void pool_kernel(const float* __restrict__ x,
                                                   const float* __restrict__ attn,
                                                   const int* __restrict__ mask,
                                                   float* __restrict__ xbar) {
    int sp = blockIdx.x, b = blockIdx.y;
    int t = threadIdx.x;
    __shared__ float at[H][PCHUNK];
    __shared__ int mk[PCHUNK];
    for (int i = t; i < H * PCHUNK; i += 256) {
        int h = i / PCHUNK, s = i % PCHUNK;
        at[h][s] = attn[((size_t)(b * H + h)) * S + sp * PCHUNK + s];
    }
    for (int i = t; i < PCHUNK; i += 256) mk[i] = mask[(size_t)b * S + sp * PCHUNK + i];
    __syncthreads();
    const float4* xr = (const float4*)(x + ((size_t)(b * S) + sp * PCHUNK) * E);
    float4 acc[H];
#pragma unroll
    for (int h = 0; h < H; ++h) acc[h] = make_float4(0.f, 0.f, 0.f, 0.f);
    for (int s = 0; s < PCHUNK; ++s) {
        if (mk[s] == 0) continue;
        float4 xv = xr[(size_t)s * (E / 4) + t];
#pragma unroll
        for (int h = 0; h < H; ++h) {
            float a = at[h][s];
            acc[h].x = fmaf(a, xv.x, acc[h].x);
            acc[h].y = fmaf(a, xv.y, acc[h].y);
            acc[h].z = fmaf(a, xv.z, acc[h].z);
            acc[h].w = fmaf(a, xv.w, acc[h].w);
        }
    }
    float* xb = xbar + (size_t)b * H * E + t * 4;
#pragma unroll
    for (int h = 0; h < H; ++h) {
        atomicAdd(&xb[h * E + 0], acc[h].x);
        atomicAdd(&xb[h * E + 1], acc[h].y);
        atomicAdd(&xb[h * E + 2], acc[h].z);
        atomicAdd(&xb[h * E + 3], acc[h].w);
    }
}

// ---------------------------------------------------------------- ctx[b][c] = bv[c] + Wv[c] . xbar[b][h(c)]
__global__ __launch_bounds__(256) void ctx_kernel(const float* __restrict__ W,
                                                  const float* __restrict__ bqkv,
                                                  const float* __restrict__ xbar,
                                                  float* __restrict__ ctx) {
    int cb = blockIdx.x, b = blockIdx.y, t = threadIdx.x;
    int c = cb * 256 + t;
    int h0 = cb * 4;
    __shared__ float xls[4 * E];  // 16 KB
    const float4* xbp = (const float4*)(xbar + ((size_t)b * H + h0) * E);
    for (int i = t; i < 4 * E / 4; i += 256) ((float4*)xls)[i] = xbp[i];
    __syncthreads();
    int h = c >> 6;
    const float4* wr = (const float4*)(W + ((size_t)(2 * E + c)) * E);
    const float4* xl = (const float4*)(xls + (h - h0) * E);
    float acc = bqkv[2 * E + c];
#pragma unroll 4
    for (int e4 = 0; e4 < E / 4; ++e4) {
        float4 w = wr[e4], xv = xl[e4];
        acc = fmaf(w.x, xv.x, acc); acc = fmaf(w.y, xv.y, acc);
        acc = fmaf(w.z, xv.z, acc); acc = fmaf(w.w, xv.w, acc);
    }
    ctx[(size_t)b * E + c] = acc;
}

// ---------------------------------------------------------------- out[b][o] = ob[o] + Wo[o] . ctx[b]
__global__ __launch_bounds__(256) void outproj_kernel(const float* __restrict__ Wo,
                                                      const float* __restrict__ ob,
                                                      const float* __restrict__ ctx,
                                                      float* __restrict__ outpre) {
    int obk = blockIdx.x, b = blockIdx.y, t = threadIdx.x;
    int o = obk * 256 + t;
    __shared__ float cl[E];  // 4 KB
    const float4* cp = (const float4*)(ctx + (size_t)b * E);
    for (int i = t; i < E / 4; i += 256) ((float4*)cl)[i] = cp[i];
    __syncthreads();
    const float4* wr = (const float4*)(Wo + (size_t)o * E);
    const float4* cl4 = (const float4*)cl;
    float acc = ob[o];
#pragma unroll 4
    for (int e4 = 0; e4 < E / 4; ++e4) {
        float4 w = wr[e4], cv = cl4[e4];
        acc = fmaf(w.x, cv.x, acc); acc = fmaf(w.y, cv.y, acc);
        acc = fmaf(w.z, cv.z, acc); acc = fmaf(w.w, cv.w, acc);
    }
    outpre[(size_t)b * E + o] = acc;
}

// ---------------------------------------------------------------- LayerNorm over E per b
__global__ __launch_bounds__(256) void ln_kernel(const float* __restrict__ outpre,
                                                 const float* __restrict__ g,
                                                 const float* __restrict__ bb,
                                                 float* __restrict__ out) {
    int b = blockIdx.x, t = threadIdx.x, lane = t & 63, wid = t >> 6;
    const float4* row = (const float4*)(outpre + (size_t)b * E);
    float4 v = row[t];
    float s = v.x + v.y + v.z + v.w;
    float sq = v.x * v.x + v.y * v.y + v.z * v.z + v.w * v.w;
    __shared__ float rs[4], rq[4];
#pragma unroll
    for (int off = 32; off > 0; off >>= 1) {
        s += __shfl_down(s, off, 64);
        sq += __shfl_down(sq, off, 64);
    }
    if (lane == 0) { rs[wid] = s; rq[wid] = sq; }
    __syncthreads();
    s = rs[0] + rs[1] + rs[2] + rs[3];
    sq = rq[0] + rq[1] + rq[2] + rq[3];
    float mean = s * (1.f / E);
    float var = sq * (1.f / E) - mean * mean;
    float inv = rsqrtf(var + 1e-5f);
    float4 gv = ((const float4*)g)[t];
    float4 bv = ((const float4*)bb)[t];
    float4 o;
    o.x = (v.x - mean) * inv * gv.x + bv.x;
    o.y = (v.y - mean) * inv * gv.y + bv.y;
    o.z = (v.z - mean) * inv * gv.z + bv.z;
    o.w = (v.w - mean) * inv * gv.w + bv.w;
    ((float4*)(out + (size_t)b * E))[t] = o;
}

extern "C" void kernel_launch(void* const* d_in, const int* in_sizes, int n_in,
                              void* d_out, int out_size, void* d_ws, size_t ws_size,
                              hipStream_t stream) {
    const float* x    = (const float*)d_in[0];
    const int*   mask = (const int*)d_in[1];
    const float* seed = (const float*)d_in[2];
    const float* W    = (const float*)d_in[3];  // (3E, E)
    const float* bqkv = (const float*)d_in[4];  // (3E,)
    const float* Wo   = (const float*)d_in[5];  // (E, E)
    const float* ob   = (const float*)d_in[6];  // (E,)
    const float* g    = (const float*)d_in[7];
    const float* lb   = (const float*)d_in[8];
    float* out = (float*)d_out;

    float* ws = (float*)d_ws;
    float* q      = ws;                          // 1024
    float* u      = q + E;                       // 16384
    float* scores = u + H * E;                   // B*H*S = 1,048,576

    qproj_kernel<<<256, 256, 0, stream>>>(W, bqkv, seed, q);
    uproj_kernel<<<dim3(E / 256, H), 256, 0, stream>>>(W, q, u);
    scores_kernel<<<512, 512, 0, stream>>>(x, mask, u, scores);
    softmax_kernel<<<B * H, 256, 0, stream>>>(scores, mask);

    size_t base = (size_t)E + H * E + (size_t)B * H * S;
    size_t needA = (base + (size_t)PS2 * B * H * E + (size_t)B * H * E + 2 * (size_t)B * E) * sizeof(float);

    float* xbar;
    float* ctx;
    float* outpre;
    if (ws_size >= needA) {
        // partials path (no atomics)
        float* part = scores + (size_t)B * H * S;        // PS2*B*H*E
        xbar   = part + (size_t)PS2 * B * H * E;         // B*H*E
        ctx    = xbar + (size_t)B * H * E;
        outpre = ctx + (size_t)B * E;
        pool3_kernel<<<dim3(PS2, B), 256, 0, stream>>>(x, scores, mask, part);
        reduce32_kernel<<<(B * H * E / 4) / 256, 256, 0, stream>>>(part, xbar);
    } else {
        // atomic fallback
        xbar   = scores + (size_t)B * H * S;
        ctx    = xbar + (size_t)B * H * E;
        outpre = ctx + (size_t)B * E;
        hipMemsetAsync(xbar, 0, (size_t)B * H * E * sizeof(float), stream);
        pool_kernel<<<dim3(PSPLIT, B), 256, 0, stream>>>(x, scores, mask, xbar);
    }

    ctx_kernel<<<dim3(E / 256, B), 256, 0, stream>>>(W, bqkv, xbar, ctx);
    outproj_kernel<<<dim3(E / 256, B), 256, 0, stream>>>(Wo, ob, ctx, outpre);
    ln_kernel<<<B, 256, 0, stream>>>(outpre, g, lb, out);
}

// Round 7
// 173.771 us; speedup vs baseline: 4.3555x; 1.0430x over previous
//
#include <hip/hip_runtime.h>
#include <math.h>

#define E 1024
#define H 16
#define HD 64
#define B 32
#define S 2048

// pool4 geometry
#define ESPL 4
#define SSPL 4
#define SLICE (E / ESPL)     // 256 floats per e-slice
#define STHR (SLICE / 2)     // 128 threads per slice (float2 each)
#define NSG (512 / STHR)     // 4 token-subgroups
#define TPB (S / SSPL)       // 512 tokens per block
#define TPSG (TPB / NSG)     // 128 tokens per subgroup
#define BHE (B * H * E)

// atomic-fallback pool geometry
#define PSPLIT 32
#define PCHUNK (S / PSPLIT)  // 64

// ---------------------------------------------------------------- q = Wq @ seed + bq
__global__ __launch_bounds__(256) void qproj_kernel(const float* __restrict__ W,
                                                    const float* __restrict__ bqkv,
                                                    const float* __restrict__ seed,
                                                    float* __restrict__ q) {
    int gw = (blockIdx.x * 256 + threadIdx.x) >> 6;  // e index
    int lane = threadIdx.x & 63;
    if (gw >= E) return;
    const float4* row = (const float4*)(W + (size_t)gw * E);
    const float4* sd = (const float4*)seed;
    float acc = 0.f;
#pragma unroll
    for (int k = 0; k < 4; ++k) {
        float4 w4 = row[k * 64 + lane];
        float4 s4 = sd[k * 64 + lane];
        acc = fmaf(w4.x, s4.x, acc); acc = fmaf(w4.y, s4.y, acc);
        acc = fmaf(w4.z, s4.z, acc); acc = fmaf(w4.w, s4.w, acc);
    }
#pragma unroll
    for (int off = 32; off > 0; off >>= 1) acc += __shfl_down(acc, off, 64);
    if (lane == 0) q[gw] = acc + bqkv[gw];
}

// ---------------------------------------------------------------- u[h][e] = scale * sum_d q[h*64+d] * Wk[h*64+d][e]
__global__ __launch_bounds__(256) void uproj_kernel(const float* __restrict__ W,
                                                    const float* __restrict__ q,
                                                    float* __restrict__ u) {
    int h = blockIdx.y;
    int e = blockIdx.x * 256 + threadIdx.x;
    __shared__ float qs[HD];
    if (threadIdx.x < HD) qs[threadIdx.x] = q[h * HD + threadIdx.x];
    __syncthreads();
    const float* Wk = W + ((size_t)(E + h * HD)) * E + e;
    float acc = 0.f;
#pragma unroll 8
    for (int d = 0; d < HD; ++d) acc = fmaf(qs[d], Wk[(size_t)d * E], acc);
    u[h * E + e] = acc * 0.125f;  // 1/sqrt(64)
}

// ---------------------------------------------------------------- scores[b][h][s] = u[h] . x[b][s]
// v5: u packed bf16 in 32 KB LDS ([e4][h ^ (e4&15)] uint2, conflict-free b64 reads),
// 2 tokens per g-group -> acc[32] (~65 VGPR), __launch_bounds__(512,6) -> 24 waves/CU.
// Butterfly over 16 m-lanes packs 32 values -> 2/lane (t=m>>3, h=2*(m&7)+{0,1}).
__global__ __launch_bounds__(512, 6) void scores_kernel(const float* __restrict__ x,
                                                        const int* __restrict__ mask,
                                                        const float* __restrict__ u,
                                                        float* __restrict__ scores) {
    __shared__ uint2 uP[4096];  // 32 KB
    for (int idx = threadIdx.x; idx < 4096; idx += 512) {
        int h = idx >> 8, e4 = idx & 255;
        float4 v = ((const float4*)(u + (size_t)h * E))[e4];
        unsigned w0 = ((__float_as_uint(v.y) + 0x8000u) & 0xffff0000u) |
                      ((__float_as_uint(v.x) + 0x8000u) >> 16);
        unsigned w1 = ((__float_as_uint(v.w) + 0x8000u) & 0xffff0000u) |
                      ((__float_as_uint(v.z) + 0x8000u) >> 16);
        uP[e4 * 16 + (h ^ (e4 & 15))] = make_uint2(w0, w1);
    }
    __syncthreads();

    int lane = threadIdx.x & 63;
    int wid = threadIdx.x >> 6;
    int m = lane & 15, g = lane >> 4;
    int gwave = blockIdx.x * 8 + wid;  // 0..8191
    int tb = gwave * 8;
    int tok0 = tb + g * 2;             // my 2 tokens
    int b0 = tok0 >> 11, s0 = tok0 & (S - 1);

    int mk0 = mask[(size_t)b0 * S + s0];
    int mk1 = mask[(size_t)b0 * S + s0 + 1];

    const float* xb = x + (size_t)tok0 * E + m * 4;

    float acc[32];
#pragma unroll
    for (int i = 0; i < 32; ++i) acc[i] = 0.f;

    for (int k = 0; k < 16; ++k) {
        float4 xv0 = make_float4(0.f, 0.f, 0.f, 0.f);
        float4 xv1 = make_float4(0.f, 0.f, 0.f, 0.f);
        if (mk0) xv0 = *(const float4*)(xb + k * 64);
        if (mk1) xv1 = *(const float4*)(xb + E + k * 64);
        const uint2* uk = uP + k * 256 + m * 16;
#pragma unroll
        for (int h = 0; h < 16; ++h) {
            uint2 up = uk[h ^ m];
            float f0 = __uint_as_float(up.x << 16);
            float f1 = __uint_as_float(up.x & 0xffff0000u);
            float f2 = __uint_as_float(up.y << 16);
            float f3 = __uint_as_float(up.y & 0xffff0000u);
            float a0 = acc[h], a1 = acc[16 + h];
            a0 = fmaf(xv0.x, f0, a0); a0 = fmaf(xv0.y, f1, a0);
            a0 = fmaf(xv0.z, f2, a0); a0 = fmaf(xv0.w, f3, a0);
            a1 = fmaf(xv1.x, f0, a1); a1 = fmaf(xv1.y, f1, a1);
            a1 = fmaf(xv1.z, f2, a1); a1 = fmaf(xv1.w, f3, a1);
            acc[h] = a0; acc[16 + h] = a1;
        }
    }

    // packing butterfly over 16 m-lanes: 32 -> 16 -> 8 -> 4 -> 2
    float w16[16];
    {
        bool up = (lane & 8) != 0;
#pragma unroll
        for (int i = 0; i < 16; ++i) {
            float lo = acc[i], hi = acc[16 + i];
            float send = up ? lo : hi, keep = up ? hi : lo;
            w16[i] = keep + __shfl_xor(send, 8, 64);
        }
    }
    float w8[8];
    {
        bool up = (lane & 4) != 0;
#pragma unroll
        for (int i = 0; i < 8; ++i) {
            float lo = w16[i], hi = w16[8 + i];
            float send = up ? lo : hi, keep = up ? hi : lo;
            w8[i] = keep + __shfl_xor(send, 4, 64);
        }
    }
    float w4a[4];
    {
        bool up = (lane & 2) != 0;
#pragma unroll
        for (int i = 0; i < 4; ++i) {
            float lo = w8[i], hi = w8[4 + i];
            float send = up ? lo : hi, keep = up ? hi : lo;
            w4a[i] = keep + __shfl_xor(send, 2, 64);
        }
    }
    float w2[2];
    {
        bool up = (lane & 1) != 0;
#pragma unroll
        for (int i = 0; i < 2; ++i) {
            float lo = w4a[i], hi = w4a[2 + i];
            float send = up ? lo : hi, keep = up ? hi : lo;
            w2[i] = keep + __shfl_xor(send, 1, 64);
        }
    }
    int t = m >> 3;
    int h = (m & 7) * 2;
    int tok = tok0 - g * 2 + g * 2 + t;  // tb + g*2 + t
    tok = tb + g * 2 + t;
    int bb = tok >> 11, s = tok & (S - 1);
    scores[((size_t)(bb * H + h)) * S + s] = w2[0];
    scores[((size_t)(bb * H + h + 1)) * S + s] = w2[1];
}

// ---------------------------------------------------------------- masked softmax over S per (b,h)
__global__ __launch_bounds__(256) void softmax_kernel(float* __restrict__ scores,
                                                      const int* __restrict__ mask) {
    int bh = blockIdx.x;
    int b = bh >> 4;
    float* row = scores + (size_t)bh * S;
    const int* mrow = mask + (size_t)b * S;
    int t = threadIdx.x, lane = t & 63, wid = t >> 6;
    float vals[8];
    float mx = -1e30f;
#pragma unroll
    for (int i = 0; i < 8; ++i) {
        int s = i * 256 + t;
        float v = row[s];
        if (mrow[s] == 0) v = -1e30f;
        vals[i] = v;
        mx = fmaxf(mx, v);
    }
    __shared__ float redm[4], reds[4];
#pragma unroll
    for (int off = 32; off > 0; off >>= 1) mx = fmaxf(mx, __shfl_down(mx, off, 64));
    if (lane == 0) redm[wid] = mx;
    __syncthreads();
    mx = fmaxf(fmaxf(redm[0], redm[1]), fmaxf(redm[2], redm[3]));
    float sum = 0.f;
#pragma unroll
    for (int i = 0; i < 8; ++i) {
        float p = __expf(vals[i] - mx);
        vals[i] = p;
        sum += p;
    }
#pragma unroll
    for (int off = 32; off > 0; off >>= 1) sum += __shfl_down(sum, off, 64);
    if (lane == 0) reds[wid] = sum;
    __syncthreads();
    sum = reds[0] + reds[1] + reds[2] + reds[3];
    float inv = 1.f / sum;
#pragma unroll
    for (int i = 0; i < 8; ++i) row[i * 256 + t] = vals[i] * inv;
}

// ---------------------------------------------------------------- pool v4: E-split partials
// grid (ESPL, SSPL, B). Block: 256-float e-slice x 512 tokens; 4 subgroups of
// 128 threads (float2/thread); attn staged [h][s] (conflict-free stage, uniform
// b128 broadcast reads); x loads skipped for masked tokens (attn==0 there);
// cross-subgroup reduce in LDS; part is only SSPL*2MB = 8 MB.
__global__ __launch_bounds__(512, 4) void pool4_kernel(const float* __restrict__ x,
                                                       const float* __restrict__ attn,
                                                       const int* __restrict__ mask,
                                                       float* __restrict__ part) {
    int ec = blockIdx.x, ss = blockIdx.y, b = blockIdx.z;
    int t = threadIdx.x;
    __shared__ float lds[NSG * H * STHR * 2];  // 64 KB: phase1 at[16][512] (32 KB), phase2 red
    __shared__ int mk[TPB];

    // stage attn [h][s] and mask
    for (int i = t; i < H * TPB; i += 512) {
        int h = i >> 9, s = i & (TPB - 1);
        lds[h * TPB + s] = attn[((size_t)(b * H + h)) * S + ss * TPB + s];
    }
    if (t < TPB) mk[t] = mask[(size_t)b * S + ss * TPB + t];
    __syncthreads();

    int l = t & (STHR - 1);   // slice lane
    int sg = t >> 7;          // subgroup
    const float* xr = x + ((size_t)b * S + ss * TPB) * E + ec * SLICE + l * 2;

    float2 acc[H];
#pragma unroll
    for (int h = 0; h < H; ++h) acc[h] = make_float2(0.f, 0.f);

    int sbase = sg * TPSG;
    for (int it = 0; it < TPSG / 4; ++it) {
        int s0 = sbase + it * 4;
        float2 xv[4];
#pragma unroll
        for (int j = 0; j < 4; ++j) {
            xv[j] = make_float2(0.f, 0.f);
            if (mk[s0 + j]) xv[j] = *(const float2*)(xr + (size_t)(s0 + j) * E);
        }
#pragma unroll
        for (int h = 0; h < 16; ++h) {
            float4 a = *(const float4*)&lds[h * TPB + s0];
            float2 ah = acc[h];
            ah.x = fmaf(a.x, xv[0].x, ah.x); ah.y = fmaf(a.x, xv[0].y, ah.y);
            ah.x = fmaf(a.y, xv[1].x, ah.x); ah.y = fmaf(a.y, xv[1].y, ah.y);
            ah.x = fmaf(a.z, xv[2].x, ah.x); ah.y = fmaf(a.z, xv[2].y, ah.y);
            ah.x = fmaf(a.w, xv[3].x, ah.x); ah.y = fmaf(a.w, xv[3].y, ah.y);
            acc[h] = ah;
        }
    }

    __syncthreads();  // done reading at
    // write subgroup partials: red[sg][h][l] float2
    float2* red = (float2*)lds;
#pragma unroll
    for (int h = 0; h < 16; ++h) red[(sg * H + h) * STHR + l] = acc[h];
    __syncthreads();

    // combine: 2048 (h,l) float2 items across 512 threads
#pragma unroll
    for (int r = 0; r < 4; ++r) {
        int id = t + r * 512;
        int h = id >> 7, ll = id & (STHR - 1);
        float2 s2 = red[h * STHR + ll];
#pragma unroll
        for (int sgi = 1; sgi < NSG; ++sgi) {
            float2 v = red[(sgi * H + h) * STHR + ll];
            s2.x += v.x; s2.y += v.y;
        }
        float2* pp = (float2*)(part + ((size_t)(ss * B + b) * H + h) * E + ec * SLICE);
        pp[ll] = s2;
    }
}

// ---------------------------------------------------------------- pool (atomic fallback)
__global__ __launch_bounds__(256) void pool_kernel(const float* __restrict__ x,
                                                   const float* __restrict__ attn,
                                                   const int* __restrict__ mask,
                                                   float* __restrict__ xbar) {
    int sp = blockIdx.x, b = blockIdx.y;
    int t = threadIdx.x;
    __shared__ float at[H][PCHUNK];
    __shared__ int mk[PCHUNK];
    for (int i = t; i < H * PCHUNK; i += 256) {
        int h = i / PCHUNK, s = i % PCHUNK;
        at[h][s] = attn[((size_t)(b * H + h)) * S + sp * PCHUNK + s];
    }
    for (int i = t; i < PCHUNK; i += 256) mk[i] = mask[(size_t)b * S + sp * PCHUNK + i];
    __syncthreads();
    const float4* xr = (const float4*)(x + ((size_t)(b * S) + sp * PCHUNK) * E);
    float4 acc[H];
#pragma unroll
    for (int h = 0; h < H; ++h) acc[h] = make_float4(0.f, 0.f, 0.f, 0.f);
    for (int s = 0; s < PCHUNK; ++s) {
        if (mk[s] == 0) continue;
        float4 xv = xr[(size_t)s * (E / 4) + t];
#pragma unroll
        for (int h = 0; h < H; ++h) {
            float a = at[h][s];
            acc[h].x = fmaf(a, xv.x, acc[h].x);
            acc[h].y = fmaf(a, xv.y, acc[h].y);
            acc[h].z = fmaf(a, xv.z, acc[h].z);
            acc[h].w = fmaf(a, xv.w, acc[h].w);
        }
    }
    float* xb = xbar + (size_t)b * H * E + t * 4;
#pragma unroll
    for (int h = 0; h < H; ++h) {
        atomicAdd(&xb[h * E + 0], acc[h].x);
        atomicAdd(&xb[h * E + 1], acc[h].y);
        atomicAdd(&xb[h * E + 2], acc[h].z);
        atomicAdd(&xb[h * E + 3], acc[h].w);
    }
}

// ---------------------------------------------------------------- ctx[b][c] = bv[c] + Wv[c] . xbar[b][h(c)]
// stages xbar = sum of nparts partial buffers (stride BHE floats)
__global__ __launch_bounds__(256) void ctx_kernel(const float* __restrict__ W,
                                                  const float* __restrict__ bqkv,
                                                  const float* __restrict__ parts,
                                                  int nparts,
                                                  float* __restrict__ ctx) {
    int cb = blockIdx.x, b = blockIdx.y, t = threadIdx.x;
    int c = cb * 256 + t;
    int h0 = cb * 4;
    __shared__ float xls[4 * E];  // 16 KB
    size_t rowoff = ((size_t)b * H + h0) * (E / 4);
    for (int i = t; i < 4 * E / 4; i += 256) {
        float4 s4 = ((const float4*)parts)[rowoff + i];
        for (int p = 1; p < nparts; ++p) {
            float4 v = ((const float4*)(parts + (size_t)p * BHE))[rowoff + i];
            s4.x += v.x; s4.y += v.y; s4.z += v.z; s4.w += v.w;
        }
        ((float4*)xls)[i] = s4;
    }
    __syncthreads();
    int h = c >> 6;
    const float4* wr = (const float4*)(W + ((size_t)(2 * E + c)) * E);
    const float4* xl = (const float4*)(xls + (h - h0) * E);
    float acc = bqkv[2 * E + c];
#pragma unroll 4
    for (int e4 = 0; e4 < E / 4; ++e4) {
        float4 w = wr[e4], xv = xl[e4];
        acc = fmaf(w.x, xv.x, acc); acc = fmaf(w.y, xv.y, acc);
        acc = fmaf(w.z, xv.z, acc); acc = fmaf(w.w, xv.w, acc);
    }
    ctx[(size_t)b * E + c] = acc;
}

// ---------------------------------------------------------------- out[b][o] = ob[o] + Wo[o] . ctx[b]
__global__ __launch_bounds__(256) void outproj_kernel(const float* __restrict__ Wo,
                                                      const float* __restrict__ ob,
                                                      const float* __restrict__ ctx,
                                                      float* __restrict__ outpre) {
    int obk = blockIdx.x, b = blockIdx.y, t = threadIdx.x;
    int o = obk * 256 + t;
    __shared__ float cl[E];  // 4 KB
    const float4* cp = (const float4*)(ctx + (size_t)b * E);
    for (int i = t; i < E / 4; i += 256) ((float4*)cl)[i] = cp[i];
    __syncthreads();
    const float4* wr = (const float4*)(Wo + (size_t)o * E);
    const float4* cl4 = (const float4*)cl;
    float acc = ob[o];
#pragma unroll 4
    for (int e4 = 0; e4 < E / 4; ++e4) {
        float4 w = wr[e4], cv = cl4[e4];
        acc = fmaf(w.x, cv.x, acc); acc = fmaf(w.y, cv.y, acc);
        acc = fmaf(w.z, cv.z, acc); acc = fmaf(w.w, cv.w, acc);
    }
    outpre[(size_t)b * E + o] = acc;
}

// ---------------------------------------------------------------- LayerNorm over E per b
__global__ __launch_bounds__(256) void ln_kernel(const float* __restrict__ outpre,
                                                 const float* __restrict__ g,
                                                 const float* __restrict__ bb,
                                                 float* __restrict__ out) {
    int b = blockIdx.x, t = threadIdx.x, lane = t & 63, wid = t >> 6;
    const float4* row = (const float4*)(outpre + (size_t)b * E);
    float4 v = row[t];
    float s = v.x + v.y + v.z + v.w;
    float sq = v.x * v.x + v.y * v.y + v.z * v.z + v.w * v.w;
    __shared__ float rs[4], rq[4];
#pragma unroll
    for (int off = 32; off > 0; off >>= 1) {
        s += __shfl_down(s, off, 64);
        sq += __shfl_down(sq, off, 64);
    }
    if (lane == 0) { rs[wid] = s; rq[wid] = sq; }
    __syncthreads();
    s = rs[0] + rs[1] + rs[2] + rs[3];
    sq = rq[0] + rq[1] + rq[2] + rq[3];
    float mean = s * (1.f / E);
    float var = sq * (1.f / E) - mean * mean;
    float inv = rsqrtf(var + 1e-5f);
    float4 gv = ((const float4*)g)[t];
    float4 bv = ((const float4*)bb)[t];
    float4 o;
    o.x = (v.x - mean) * inv * gv.x + bv.x;
    o.y = (v.y - mean) * inv * gv.y + bv.y;
    o.z = (v.z - mean) * inv * gv.z + bv.z;
    o.w = (v.w - mean) * inv * gv.w + bv.w;
    ((float4*)(out + (size_t)b * E))[t] = o;
}

extern "C" void kernel_launch(void* const* d_in, const int* in_sizes, int n_in,
                              void* d_out, int out_size, void* d_ws, size_t ws_size,
                              hipStream_t stream) {
    const float* x    = (const float*)d_in[0];
    const int*   mask = (const int*)d_in[1];
    const float* seed = (const float*)d_in[2];
    const float* W    = (const float*)d_in[3];  // (3E, E)
    const float* bqkv = (const float*)d_in[4];  // (3E,)
    const float* Wo   = (const float*)d_in[5];  // (E, E)
    const float* ob   = (const float*)d_in[6];  // (E,)
    const float* g    = (const float*)d_in[7];
    const float* lb   = (const float*)d_in[8];
    float* out = (float*)d_out;

    float* ws = (float*)d_ws;
    float* q      = ws;                          // 1024
    float* u      = q + E;                       // 16384
    float* scores = u + H * E;                   // B*H*S = 1,048,576

    qproj_kernel<<<256, 256, 0, stream>>>(W, bqkv, seed, q);
    uproj_kernel<<<dim3(E / 256, H), 256, 0, stream>>>(W, q, u);
    scores_kernel<<<1024, 512, 0, stream>>>(x, mask, u, scores);
    softmax_kernel<<<B * H, 256, 0, stream>>>(scores, mask);

    size_t base = (size_t)E + H * E + (size_t)B * H * S;
    size_t needA = (base + (size_t)SSPL * BHE + 2 * (size_t)B * E) * sizeof(float);

    float* ctx;
    float* outpre;
    if (ws_size >= needA) {
        // E-split partials path
        float* part = scores + (size_t)B * H * S;   // SSPL*BHE
        ctx    = part + (size_t)SSPL * BHE;
        outpre = ctx + (size_t)B * E;
        pool4_kernel<<<dim3(ESPL, SSPL, B), 512, 0, stream>>>(x, scores, mask, part);
        ctx_kernel<<<dim3(E / 256, B), 256, 0, stream>>>(W, bqkv, part, SSPL, ctx);
    } else {
        // atomic fallback
        float* xbar = scores + (size_t)B * H * S;
        ctx    = xbar + (size_t)BHE;
        outpre = ctx + (size_t)B * E;
        hipMemsetAsync(xbar, 0, (size_t)BHE * sizeof(float), stream);
        pool_kernel<<<dim3(PSPLIT, B), 256, 0, stream>>>(x, scores, mask, xbar);
        ctx_kernel<<<dim3(E / 256, B), 256, 0, stream>>>(W, bqkv, xbar, 1, ctx);
    }

    outproj_kernel<<<dim3(E / 256, B), 256, 0, stream>>>(Wo, ob, ctx, outpre);
    ln_kernel<<<B, 256, 0, stream>>>(outpre, g, lb, out);
}

// Round 8
// 168.649 us; speedup vs baseline: 4.4878x; 1.0304x over previous
//
#include <hip/hip_runtime.h>
#include <math.h>

#define E 1024
#define H 16
#define HD 64
#define B 32
#define S 2048
#define CH 16          // token chunks per batch row
#define CTOK (S / CH)  // 128 tokens per chunk
#define BHE (B * H * E)

// ---------------------------------------------------------------- q = Wq @ seed + bq
__global__ __launch_bounds__(256) void qproj_kernel(const float* __restrict__ W,
                                                    const float* __restrict__ bqkv,
                                                    const float* __restrict__ seed,
                                                    float* __restrict__ q) {
    int gw = (blockIdx.x * 256 + threadIdx.x) >> 6;  // e index
    int lane = threadIdx.x & 63;
    if (gw >= E) return;
    const float4* row = (const float4*)(W + (size_t)gw * E);
    const float4* sd = (const float4*)seed;
    float acc = 0.f;
#pragma unroll
    for (int k = 0; k < 4; ++k) {
        float4 w4 = row[k * 64 + lane];
        float4 s4 = sd[k * 64 + lane];
        acc = fmaf(w4.x, s4.x, acc); acc = fmaf(w4.y, s4.y, acc);
        acc = fmaf(w4.z, s4.z, acc); acc = fmaf(w4.w, s4.w, acc);
    }
#pragma unroll
    for (int off = 32; off > 0; off >>= 1) acc += __shfl_down(acc, off, 64);
    if (lane == 0) q[gw] = acc + bqkv[gw];
}

// ---------------------------------------------------------------- u[h][e] = scale * sum_d q[h*64+d] * Wk[h*64+d][e]
__global__ __launch_bounds__(256) void uproj_kernel(const float* __restrict__ W,
                                                    const float* __restrict__ q,
                                                    float* __restrict__ u) {
    int h = blockIdx.y;
    int e = blockIdx.x * 256 + threadIdx.x;
    __shared__ float qs[HD];
    if (threadIdx.x < HD) qs[threadIdx.x] = q[h * HD + threadIdx.x];
    __syncthreads();
    const float* Wk = W + ((size_t)(E + h * HD)) * E + e;
    float acc = 0.f;
#pragma unroll 8
    for (int d = 0; d < HD; ++d) acc = fmaf(qs[d], Wk[(size_t)d * E], acc);
    u[h * E + e] = acc * 0.125f;  // 1/sqrt(64)
}

// ---------------------------------------------------------------- fused scores+softmax+pool per (chunk, b)
// Phase 1: v3 score MAC structure -> 128x16 score tile in LDS (no global scores).
// Phase 1.5: masked tile softmax: tile max m[h], p=exp(s-m), tile sum l[h] (online partials).
// Phase 2: each wave owns a 128-float e-slice; re-reads the block's x slice (L2/L3-hot)
// and accumulates p*x into 32 regs; writes one unnormalized 64-KB partial + (m,l) stats.
__global__ __launch_bounds__(512, 4) void fused_kernel(const float* __restrict__ x,
                                                       const int* __restrict__ mask,
                                                       const float* __restrict__ u,
                                                       float* __restrict__ part,
                                                       float* __restrict__ mstat,
                                                       float* __restrict__ lstat) {
    int ss = blockIdx.x, b = blockIdx.y;
    __shared__ float4 uT[4096];      // 64 KB  [e4][h ^ (e4&7)]
    __shared__ float sc[CTOK * 16];  // 8 KB   scores then p, [tok][h]
    __shared__ int mk[CTOK];
    __shared__ float4 redm[32];      // cross-wave reduce: [wave][hq]
    __shared__ float mxs[16], lls[16];

    int tid = threadIdx.x;
    for (int idx = tid; idx < 4096; idx += 512) {
        int h = idx >> 8, e4 = idx & 255;
        uT[e4 * 16 + (h ^ (e4 & 7))] = ((const float4*)(u + (size_t)h * E))[e4];
    }
    if (tid < CTOK) mk[tid] = mask[(size_t)b * S + ss * CTOK + tid];
    __syncthreads();

    int lane = tid & 63, wid = tid >> 6;
    int m = lane & 15, g = lane >> 4;
    int tl0 = wid * 16 + g * 4;  // local token base of this lane's 4-token group

    // ---- phase 1: scores ----
    {
        int mkr[4];
#pragma unroll
        for (int t = 0; t < 4; ++t) mkr[t] = mk[tl0 + t];
        const float* xb = x + ((size_t)b * S + ss * CTOK + tl0) * E + m * 4;

        float acc[64];
#pragma unroll
        for (int i = 0; i < 64; ++i) acc[i] = 0.f;

        for (int k = 0; k < 16; ++k) {
            float4 xv[4];
#pragma unroll
            for (int t = 0; t < 4; ++t) {
                xv[t] = make_float4(0.f, 0.f, 0.f, 0.f);
                if (mkr[t]) xv[t] = *(const float4*)(xb + (size_t)t * E + k * 64);
            }
            const float4* uk = uT + k * 256 + m * 16;
            int sw = m & 7;
#pragma unroll
            for (int h = 0; h < 16; ++h) {
                float4 uv = uk[h ^ sw];
#pragma unroll
                for (int t = 0; t < 4; ++t) {
                    acc[t * 16 + h] = fmaf(xv[t].x, uv.x, acc[t * 16 + h]);
                    acc[t * 16 + h] = fmaf(xv[t].y, uv.y, acc[t * 16 + h]);
                    acc[t * 16 + h] = fmaf(xv[t].z, uv.z, acc[t * 16 + h]);
                    acc[t * 16 + h] = fmaf(xv[t].w, uv.w, acc[t * 16 + h]);
                }
            }
        }

        // packing butterfly over the 16 m-lanes: 64 -> 32 -> 16 -> 8 -> 4 values
        float v32[32];
        {
            bool up = (lane & 8) != 0;
#pragma unroll
            for (int i = 0; i < 32; ++i) {
                float lo = acc[i], hi = acc[32 + i];
                float send = up ? lo : hi, keep = up ? hi : lo;
                v32[i] = keep + __shfl_xor(send, 8, 64);
            }
        }
        float v16[16];
        {
            bool up = (lane & 4) != 0;
#pragma unroll
            for (int i = 0; i < 16; ++i) {
                float lo = v32[i], hi = v32[16 + i];
                float send = up ? lo : hi, keep = up ? hi : lo;
                v16[i] = keep + __shfl_xor(send, 4, 64);
            }
        }
        float v8a[8];
        {
            bool up = (lane & 2) != 0;
#pragma unroll
            for (int i = 0; i < 8; ++i) {
                float lo = v16[i], hi = v16[8 + i];
                float send = up ? lo : hi, keep = up ? hi : lo;
                v8a[i] = keep + __shfl_xor(send, 2, 64);
            }
        }
        float v4a[4];
        {
            bool up = (lane & 1) != 0;
#pragma unroll
            for (int i = 0; i < 4; ++i) {
                float lo = v8a[i], hi = v8a[4 + i];
                float send = up ? lo : hi, keep = up ? hi : lo;
                v4a[i] = keep + __shfl_xor(send, 1, 64);
            }
        }
        int t = m >> 2;
        int h0 = (m & 3) * 4;
        int tl = wid * 16 + g * 4 + t;
        *(float4*)&sc[tl * 16 + h0] = make_float4(v4a[0], v4a[1], v4a[2], v4a[3]);
    }
    __syncthreads();

    // ---- phase 1.5: masked tile softmax -> p in sc, stats (m,l) ----
    {
        int tok = tid >> 2, hq = tid & 3;  // lane == (tok&15)*4 + hq
        float4 s4 = *(const float4*)&sc[tok * 16 + hq * 4];
        bool live = mk[tok] != 0;
        float4 sm = live ? s4 : make_float4(-1e30f, -1e30f, -1e30f, -1e30f);
#pragma unroll
        for (int off = 4; off <= 32; off <<= 1) {
            sm.x = fmaxf(sm.x, __shfl_xor(sm.x, off, 64));
            sm.y = fmaxf(sm.y, __shfl_xor(sm.y, off, 64));
            sm.z = fmaxf(sm.z, __shfl_xor(sm.z, off, 64));
            sm.w = fmaxf(sm.w, __shfl_xor(sm.w, off, 64));
        }
        if (lane < 4) redm[wid * 4 + lane] = sm;
        __syncthreads();
        if (tid < 4) {
            float4 mm = redm[tid];
#pragma unroll
            for (int w = 1; w < 8; ++w) {
                float4 v = redm[w * 4 + tid];
                mm.x = fmaxf(mm.x, v.x); mm.y = fmaxf(mm.y, v.y);
                mm.z = fmaxf(mm.z, v.z); mm.w = fmaxf(mm.w, v.w);
            }
            *(float4*)&mxs[tid * 4] = mm;
        }
        __syncthreads();
        float4 mx4 = *(const float4*)&mxs[hq * 4];
        float4 p4 = make_float4(0.f, 0.f, 0.f, 0.f);
        if (live) {
            p4.x = __expf(s4.x - mx4.x);
            p4.y = __expf(s4.y - mx4.y);
            p4.z = __expf(s4.z - mx4.z);
            p4.w = __expf(s4.w - mx4.w);
        }
        *(float4*)&sc[tok * 16 + hq * 4] = p4;
        float4 l4 = p4;
#pragma unroll
        for (int off = 4; off <= 32; off <<= 1) {
            l4.x += __shfl_xor(l4.x, off, 64);
            l4.y += __shfl_xor(l4.y, off, 64);
            l4.z += __shfl_xor(l4.z, off, 64);
            l4.w += __shfl_xor(l4.w, off, 64);
        }
        __syncthreads();  // redm reuse
        if (lane < 4) redm[wid * 4 + lane] = l4;
        __syncthreads();
        if (tid < 4) {
            float4 sl = redm[tid];
#pragma unroll
            for (int w = 1; w < 8; ++w) {
                float4 v = redm[w * 4 + tid];
                sl.x += v.x; sl.y += v.y; sl.z += v.z; sl.w += v.w;
            }
            *(float4*)&lls[tid * 4] = sl;
        }
        __syncthreads();
        if (tid < 16) {
            mstat[((size_t)ss * B + b) * H + tid] = mxs[tid];
            lstat[((size_t)ss * B + b) * H + tid] = lls[tid];
        }
    }

    // ---- phase 2: accumulate p * x into per-wave e-slice registers ----
    {
        float2 a2[16];
#pragma unroll
        for (int h = 0; h < 16; ++h) a2[h] = make_float2(0.f, 0.f);
        const float* xp = x + ((size_t)b * S + ss * CTOK) * E + wid * 128 + lane * 2;
        const float4* sc4 = (const float4*)sc;
        for (int tok = 0; tok < CTOK; ++tok) {
            if (!mk[tok]) continue;
            float2 xv = *(const float2*)(xp + (size_t)tok * E);
            float4 p0 = sc4[tok * 4 + 0];
            float4 p1 = sc4[tok * 4 + 1];
            float4 p2 = sc4[tok * 4 + 2];
            float4 p3 = sc4[tok * 4 + 3];
            a2[0].x = fmaf(p0.x, xv.x, a2[0].x);   a2[0].y = fmaf(p0.x, xv.y, a2[0].y);
            a2[1].x = fmaf(p0.y, xv.x, a2[1].x);   a2[1].y = fmaf(p0.y, xv.y, a2[1].y);
            a2[2].x = fmaf(p0.z, xv.x, a2[2].x);   a2[2].y = fmaf(p0.z, xv.y, a2[2].y);
            a2[3].x = fmaf(p0.w, xv.x, a2[3].x);   a2[3].y = fmaf(p0.w, xv.y, a2[3].y);
            a2[4].x = fmaf(p1.x, xv.x, a2[4].x);   a2[4].y = fmaf(p1.x, xv.y, a2[4].y);
            a2[5].x = fmaf(p1.y, xv.x, a2[5].x);   a2[5].y = fmaf(p1.y, xv.y, a2[5].y);
            a2[6].x = fmaf(p1.z, xv.x, a2[6].x);   a2[6].y = fmaf(p1.z, xv.y, a2[6].y);
            a2[7].x = fmaf(p1.w, xv.x, a2[7].x);   a2[7].y = fmaf(p1.w, xv.y, a2[7].y);
            a2[8].x = fmaf(p2.x, xv.x, a2[8].x);   a2[8].y = fmaf(p2.x, xv.y, a2[8].y);
            a2[9].x = fmaf(p2.y, xv.x, a2[9].x);   a2[9].y = fmaf(p2.y, xv.y, a2[9].y);
            a2[10].x = fmaf(p2.z, xv.x, a2[10].x); a2[10].y = fmaf(p2.z, xv.y, a2[10].y);
            a2[11].x = fmaf(p2.w, xv.x, a2[11].x); a2[11].y = fmaf(p2.w, xv.y, a2[11].y);
            a2[12].x = fmaf(p3.x, xv.x, a2[12].x); a2[12].y = fmaf(p3.x, xv.y, a2[12].y);
            a2[13].x = fmaf(p3.y, xv.x, a2[13].x); a2[13].y = fmaf(p3.y, xv.y, a2[13].y);
            a2[14].x = fmaf(p3.z, xv.x, a2[14].x); a2[14].y = fmaf(p3.z, xv.y, a2[14].y);
            a2[15].x = fmaf(p3.w, xv.x, a2[15].x); a2[15].y = fmaf(p3.w, xv.y, a2[15].y);
        }
        float* pb = part + ((size_t)ss * B + b) * (H * E) + wid * 128 + lane * 2;
#pragma unroll
        for (int h = 0; h < 16; ++h) *(float2*)(pb + (size_t)h * E) = a2[h];
    }
}

// ---------------------------------------------------------------- combine: xbar[b][h] = sum_c f_c*acc_c / sum_c f_c*l_c
__global__ __launch_bounds__(256) void combine_kernel(const float* __restrict__ part,
                                                      const float* __restrict__ mstat,
                                                      const float* __restrict__ lstat,
                                                      float* __restrict__ xbar) {
    int h = blockIdx.x, b = blockIdx.y, t = threadIdx.x;
    __shared__ float f[CH];
    __shared__ float linv;
    if (t == 0) {
        float mv[CH];
        float mg = -1e30f;
#pragma unroll
        for (int c = 0; c < CH; ++c) {
            mv[c] = mstat[((size_t)c * B + b) * H + h];
            mg = fmaxf(mg, mv[c]);
        }
        float l = 0.f;
#pragma unroll
        for (int c = 0; c < CH; ++c) {
            float fc = __expf(mv[c] - mg);
            f[c] = fc;
            l = fmaf(fc, lstat[((size_t)c * B + b) * H + h], l);
        }
        linv = 1.f / l;
    }
    __syncthreads();
    float4 s = make_float4(0.f, 0.f, 0.f, 0.f);
    const float4* p4 = (const float4*)part;
#pragma unroll 4
    for (int c = 0; c < CH; ++c) {
        float4 v = p4[(((size_t)c * B + b) * H + h) * (E / 4) + t];
        float fc = f[c];
        s.x = fmaf(fc, v.x, s.x); s.y = fmaf(fc, v.y, s.y);
        s.z = fmaf(fc, v.z, s.z); s.w = fmaf(fc, v.w, s.w);
    }
    s.x *= linv; s.y *= linv; s.z *= linv; s.w *= linv;
    ((float4*)xbar)[((size_t)b * H + h) * (E / 4) + t] = s;
}

// ---------------------------------------------------------------- ctx[b][c] = bv[c] + Wv[c] . xbar[b][h(c)]
__global__ __launch_bounds__(256) void ctx_kernel(const float* __restrict__ W,
                                                  const float* __restrict__ bqkv,
                                                  const float* __restrict__ xbar,
                                                  float* __restrict__ ctx) {
    int cb = blockIdx.x, b = blockIdx.y, t = threadIdx.x;
    int c = cb * 256 + t;
    int h0 = cb * 4;
    __shared__ float xls[4 * E];  // 16 KB
    const float4* xbp = (const float4*)(xbar + ((size_t)b * H + h0) * E);
    for (int i = t; i < 4 * E / 4; i += 256) ((float4*)xls)[i] = xbp[i];
    __syncthreads();
    int h = c >> 6;
    const float4* wr = (const float4*)(W + ((size_t)(2 * E + c)) * E);
    const float4* xl = (const float4*)(xls + (h - h0) * E);
    float acc = bqkv[2 * E + c];
#pragma unroll 4
    for (int e4 = 0; e4 < E / 4; ++e4) {
        float4 w = wr[e4], xv = xl[e4];
        acc = fmaf(w.x, xv.x, acc); acc = fmaf(w.y, xv.y, acc);
        acc = fmaf(w.z, xv.z, acc); acc = fmaf(w.w, xv.w, acc);
    }
    ctx[(size_t)b * E + c] = acc;
}

// ---------------------------------------------------------------- out[b][o] = ob[o] + Wo[o] . ctx[b]
__global__ __launch_bounds__(256) void outproj_kernel(const float* __restrict__ Wo,
                                                      const float* __restrict__ ob,
                                                      const float* __restrict__ ctx,
                                                      float* __restrict__ outpre) {
    int obk = blockIdx.x, b = blockIdx.y, t = threadIdx.x;
    int o = obk * 256 + t;
    __shared__ float cl[E];  // 4 KB
    const float4* cp = (const float4*)(ctx + (size_t)b * E);
    for (int i = t; i < E / 4; i += 256) ((float4*)cl)[i] = cp[i];
    __syncthreads();
    const float4* wr = (const float4*)(Wo + (size_t)o * E);
    const float4* cl4 = (const float4*)cl;
    float acc = ob[o];
#pragma unroll 4
    for (int e4 = 0; e4 < E / 4; ++e4) {
        float4 w = wr[e4], cv = cl4[e4];
        acc = fmaf(w.x, cv.x, acc); acc = fmaf(w.y, cv.y, acc);
        acc = fmaf(w.z, cv.z, acc); acc = fmaf(w.w, cv.w, acc);
    }
    outpre[(size_t)b * E + o] = acc;
}

// ---------------------------------------------------------------- LayerNorm over E per b
__global__ __launch_bounds__(256) void ln_kernel(const float* __restrict__ outpre,
                                                 const float* __restrict__ g,
                                                 const float* __restrict__ bb,
                                                 float* __restrict__ out) {
    int b = blockIdx.x, t = threadIdx.x, lane = t & 63, wid = t >> 6;
    const float4* row = (const float4*)(outpre + (size_t)b * E);
    float4 v = row[t];
    float s = v.x + v.y + v.z + v.w;
    float sq = v.x * v.x + v.y * v.y + v.z * v.z + v.w * v.w;
    __shared__ float rs[4], rq[4];
#pragma unroll
    for (int off = 32; off > 0; off >>= 1) {
        s += __shfl_down(s, off, 64);
        sq += __shfl_down(sq, off, 64);
    }
    if (lane == 0) { rs[wid] = s; rq[wid] = sq; }
    __syncthreads();
    s = rs[0] + rs[1] + rs[2] + rs[3];
    sq = rq[0] + rq[1] + rq[2] + rq[3];
    float mean = s * (1.f / E);
    float var = sq * (1.f / E) - mean * mean;
    float inv = rsqrtf(var + 1e-5f);
    float4 gv = ((const float4*)g)[t];
    float4 bv = ((const float4*)bb)[t];
    float4 o;
    o.x = (v.x - mean) * inv * gv.x + bv.x;
    o.y = (v.y - mean) * inv * gv.y + bv.y;
    o.z = (v.z - mean) * inv * gv.z + bv.z;
    o.w = (v.w - mean) * inv * gv.w + bv.w;
    ((float4*)(out + (size_t)b * E))[t] = o;
}

extern "C" void kernel_launch(void* const* d_in, const int* in_sizes, int n_in,
                              void* d_out, int out_size, void* d_ws, size_t ws_size,
                              hipStream_t stream) {
    const float* x    = (const float*)d_in[0];
    const int*   mask = (const int*)d_in[1];
    const float* seed = (const float*)d_in[2];
    const float* W    = (const float*)d_in[3];  // (3E, E)
    const float* bqkv = (const float*)d_in[4];  // (3E,)
    const float* Wo   = (const float*)d_in[5];  // (E, E)
    const float* ob   = (const float*)d_in[6];  // (E,)
    const float* g    = (const float*)d_in[7];
    const float* lb   = (const float*)d_in[8];
    float* out = (float*)d_out;

    float* ws = (float*)d_ws;
    float* q      = ws;                           // E
    float* u      = q + E;                        // H*E
    float* part   = u + H * E;                    // CH*B*H*E = 8,388,608
    float* mstat  = part + (size_t)CH * BHE;      // CH*B*H
    float* lstat  = mstat + (size_t)CH * B * H;   // CH*B*H
    float* xbar   = lstat + (size_t)CH * B * H;   // B*H*E
    float* ctx    = xbar + (size_t)BHE;           // B*E
    float* outpre = ctx + (size_t)B * E;          // B*E

    qproj_kernel<<<256, 256, 0, stream>>>(W, bqkv, seed, q);
    uproj_kernel<<<dim3(E / 256, H), 256, 0, stream>>>(W, q, u);
    fused_kernel<<<dim3(CH, B), 512, 0, stream>>>(x, mask, u, part, mstat, lstat);
    combine_kernel<<<dim3(H, B), 256, 0, stream>>>(part, mstat, lstat, xbar);
    ctx_kernel<<<dim3(E / 256, B), 256, 0, stream>>>(W, bqkv, xbar, ctx);
    outproj_kernel<<<dim3(E / 256, B), 256, 0, stream>>>(Wo, ob, ctx, outpre);
    ln_kernel<<<B, 256, 0, stream>>>(outpre, g, lb, out);
}

// Round 9
// 148.804 us; speedup vs baseline: 5.0863x; 1.1334x over previous
//
#include <hip/hip_runtime.h>
#include <hip/hip_bf16.h>
#include <math.h>

#define E 1024
#define H 16
#define HD 64
#define B 32
#define S 2048
#define CH 16          // token chunks per batch row
#define CTOK (S / CH)  // 128 tokens per chunk
#define BHE (B * H * E)

typedef __attribute__((ext_vector_type(8))) short short8;
typedef __attribute__((ext_vector_type(4))) float f32x4;

__device__ __forceinline__ short f2bf(float f) {
    union { __hip_bfloat16 h; short s; } u;
    u.h = __float2bfloat16(f);
    return u.s;
}

// ---------------------------------------------------------------- q = Wq @ seed + bq
__global__ __launch_bounds__(256) void qproj_kernel(const float* __restrict__ W,
                                                    const float* __restrict__ bqkv,
                                                    const float* __restrict__ seed,
                                                    float* __restrict__ q) {
    int gw = (blockIdx.x * 256 + threadIdx.x) >> 6;  // e index
    int lane = threadIdx.x & 63;
    if (gw >= E) return;
    const float4* row = (const float4*)(W + (size_t)gw * E);
    const float4* sd = (const float4*)seed;
    float acc = 0.f;
#pragma unroll
    for (int k = 0; k < 4; ++k) {
        float4 w4 = row[k * 64 + lane];
        float4 s4 = sd[k * 64 + lane];
        acc = fmaf(w4.x, s4.x, acc); acc = fmaf(w4.y, s4.y, acc);
        acc = fmaf(w4.z, s4.z, acc); acc = fmaf(w4.w, s4.w, acc);
    }
#pragma unroll
    for (int off = 32; off > 0; off >>= 1) acc += __shfl_down(acc, off, 64);
    if (lane == 0) q[gw] = acc + bqkv[gw];
}

// ---------------------------------------------------------------- u[h][e] = scale * sum_d q[h*64+d] * Wk[h*64+d][e]
__global__ __launch_bounds__(256) void uproj_kernel(const float* __restrict__ W,
                                                    const float* __restrict__ q,
                                                    float* __restrict__ u) {
    int h = blockIdx.y;
    int e = blockIdx.x * 256 + threadIdx.x;
    __shared__ float qs[HD];
    if (threadIdx.x < HD) qs[threadIdx.x] = q[h * HD + threadIdx.x];
    __syncthreads();
    const float* Wk = W + ((size_t)(E + h * HD)) * E + e;
    float acc = 0.f;
#pragma unroll 8
    for (int d = 0; d < HD; ++d) acc = fmaf(qs[d], Wk[(size_t)d * E], acc);
    u[h * E + e] = acc * 0.125f;  // 1/sqrt(64)
}

// ---------------------------------------------------------------- fused scores(MFMA)+softmax+pool per (chunk, b)
// Phase 1: scores = X . u^T via mfma_f32_16x16x32_bf16. Wave = one 16-tok x 16-head
//   C-tile, K=1024 = 32 MFMA. A-frag: lane = (tok=l&15, kg=l>>4), 2 coalesced float4
//   loads + cvt to bf16. B-frag: u bf16 in LDS, unit [e>>3][h] -> conflict-free b128.
//   C layout: col(lane&15)=head, row((lane>>4)*4+r)=token (m89-verified mapping).
// Phase 1.5: masked tile softmax (max, p=exp(s-m), sum) -> online partial stats.
// Phase 2: wave owns a 128-float e-slice, accumulates p*x (fp32, x from L2/L3).
__global__ __launch_bounds__(512, 4) void fused_kernel(const float* __restrict__ x,
                                                       const int* __restrict__ mask,
                                                       const float* __restrict__ u,
                                                       float* __restrict__ part,
                                                       float* __restrict__ mstat,
                                                       float* __restrict__ lstat) {
    int ss = blockIdx.x, b = blockIdx.y;
    __shared__ short uB[H * E];      // 32 KB bf16, unit layout [(e>>3)*16 + h] of bf16x8
    __shared__ float sc[CTOK * 16];  // 8 KB  scores then p, [tok][h]
    __shared__ int mk[CTOK];
    __shared__ float4 redm[32];      // cross-wave reduce: [wave][hq]
    __shared__ float mxs[16], lls[16];

    int tid = threadIdx.x;
    // stage u -> bf16 LDS
    for (int un = tid; un < 2048; un += 512) {
        int h = un & 15, e8 = un >> 4;
        const float* up = u + (size_t)h * E + e8 * 8;
        short8 v;
#pragma unroll
        for (int j = 0; j < 8; ++j) v[j] = f2bf(up[j]);
        ((short8*)uB)[un] = v;
    }
    if (tid < CTOK) mk[tid] = mask[(size_t)b * S + ss * CTOK + tid];
    __syncthreads();

    int lane = tid & 63, wid = tid >> 6;

    // ---- phase 1: MFMA scores ----
    {
        int tl0 = wid * 16;
        int tr = lane & 15;     // A-row (token) / B-col (head) / C-col (head)
        int kg = lane >> 4;     // k-group
        int myTok = tl0 + tr;
        bool live = mk[myTok] != 0;
        const float* xrow = x + ((size_t)b * S + ss * CTOK + myTok) * E + kg * 8;
        const short8* uB8 = (const short8*)uB;

        f32x4 acc = {0.f, 0.f, 0.f, 0.f};
#pragma unroll 4
        for (int st = 0; st < 32; ++st) {
            float4 lo = make_float4(0.f, 0.f, 0.f, 0.f);
            float4 hi = make_float4(0.f, 0.f, 0.f, 0.f);
            if (live) {
                lo = *(const float4*)(xrow + st * 32);
                hi = *(const float4*)(xrow + st * 32 + 4);
            }
            short8 a;
            a[0] = f2bf(lo.x); a[1] = f2bf(lo.y); a[2] = f2bf(lo.z); a[3] = f2bf(lo.w);
            a[4] = f2bf(hi.x); a[5] = f2bf(hi.y); a[6] = f2bf(hi.z); a[7] = f2bf(hi.w);
            short8 bf = uB8[(st * 4 + kg) * 16 + tr];
            acc = __builtin_amdgcn_mfma_f32_16x16x32_bf16(a, bf, acc, 0, 0, 0);
        }
        int r0 = kg * 4;
#pragma unroll
        for (int r = 0; r < 4; ++r)
            sc[(tl0 + r0 + r) * 16 + tr] = acc[r];
    }
    __syncthreads();

    // ---- phase 1.5: masked tile softmax -> p in sc, stats (m,l) ----
    {
        int tok = tid >> 2, hq = tid & 3;
        float4 s4 = *(const float4*)&sc[tok * 16 + hq * 4];
        bool live = mk[tok] != 0;
        float4 sm = live ? s4 : make_float4(-1e30f, -1e30f, -1e30f, -1e30f);
#pragma unroll
        for (int off = 4; off <= 32; off <<= 1) {
            sm.x = fmaxf(sm.x, __shfl_xor(sm.x, off, 64));
            sm.y = fmaxf(sm.y, __shfl_xor(sm.y, off, 64));
            sm.z = fmaxf(sm.z, __shfl_xor(sm.z, off, 64));
            sm.w = fmaxf(sm.w, __shfl_xor(sm.w, off, 64));
        }
        if (lane < 4) redm[wid * 4 + lane] = sm;
        __syncthreads();
        if (tid < 4) {
            float4 mm = redm[tid];
#pragma unroll
            for (int w = 1; w < 8; ++w) {
                float4 v = redm[w * 4 + tid];
                mm.x = fmaxf(mm.x, v.x); mm.y = fmaxf(mm.y, v.y);
                mm.z = fmaxf(mm.z, v.z); mm.w = fmaxf(mm.w, v.w);
            }
            *(float4*)&mxs[tid * 4] = mm;
        }
        __syncthreads();
        float4 mx4 = *(const float4*)&mxs[hq * 4];
        float4 p4 = make_float4(0.f, 0.f, 0.f, 0.f);
        if (live) {
            p4.x = __expf(s4.x - mx4.x);
            p4.y = __expf(s4.y - mx4.y);
            p4.z = __expf(s4.z - mx4.z);
            p4.w = __expf(s4.w - mx4.w);
        }
        *(float4*)&sc[tok * 16 + hq * 4] = p4;
        float4 l4 = p4;
#pragma unroll
        for (int off = 4; off <= 32; off <<= 1) {
            l4.x += __shfl_xor(l4.x, off, 64);
            l4.y += __shfl_xor(l4.y, off, 64);
            l4.z += __shfl_xor(l4.z, off, 64);
            l4.w += __shfl_xor(l4.w, off, 64);
        }
        __syncthreads();  // redm reuse
        if (lane < 4) redm[wid * 4 + lane] = l4;
        __syncthreads();
        if (tid < 4) {
            float4 sl = redm[tid];
#pragma unroll
            for (int w = 1; w < 8; ++w) {
                float4 v = redm[w * 4 + tid];
                sl.x += v.x; sl.y += v.y; sl.z += v.z; sl.w += v.w;
            }
            *(float4*)&lls[tid * 4] = sl;
        }
        __syncthreads();
        if (tid < 16) {
            mstat[((size_t)ss * B + b) * H + tid] = mxs[tid];
            lstat[((size_t)ss * B + b) * H + tid] = lls[tid];
        }
    }

    // ---- phase 2: accumulate p * x into per-wave e-slice registers ----
    {
        float2 a2[16];
#pragma unroll
        for (int h = 0; h < 16; ++h) a2[h] = make_float2(0.f, 0.f);
        const float* xp = x + ((size_t)b * S + ss * CTOK) * E + wid * 128 + lane * 2;
        const float4* sc4 = (const float4*)sc;
        for (int tok = 0; tok < CTOK; ++tok) {
            if (!mk[tok]) continue;
            float2 xv = *(const float2*)(xp + (size_t)tok * E);
            float4 p0 = sc4[tok * 4 + 0];
            float4 p1 = sc4[tok * 4 + 1];
            float4 p2 = sc4[tok * 4 + 2];
            float4 p3 = sc4[tok * 4 + 3];
            a2[0].x = fmaf(p0.x, xv.x, a2[0].x);   a2[0].y = fmaf(p0.x, xv.y, a2[0].y);
            a2[1].x = fmaf(p0.y, xv.x, a2[1].x);   a2[1].y = fmaf(p0.y, xv.y, a2[1].y);
            a2[2].x = fmaf(p0.z, xv.x, a2[2].x);   a2[2].y = fmaf(p0.z, xv.y, a2[2].y);
            a2[3].x = fmaf(p0.w, xv.x, a2[3].x);   a2[3].y = fmaf(p0.w, xv.y, a2[3].y);
            a2[4].x = fmaf(p1.x, xv.x, a2[4].x);   a2[4].y = fmaf(p1.x, xv.y, a2[4].y);
            a2[5].x = fmaf(p1.y, xv.x, a2[5].x);   a2[5].y = fmaf(p1.y, xv.y, a2[5].y);
            a2[6].x = fmaf(p1.z, xv.x, a2[6].x);   a2[6].y = fmaf(p1.z, xv.y, a2[6].y);
            a2[7].x = fmaf(p1.w, xv.x, a2[7].x);   a2[7].y = fmaf(p1.w, xv.y, a2[7].y);
            a2[8].x = fmaf(p2.x, xv.x, a2[8].x);   a2[8].y = fmaf(p2.x, xv.y, a2[8].y);
            a2[9].x = fmaf(p2.y, xv.x, a2[9].x);   a2[9].y = fmaf(p2.y, xv.y, a2[9].y);
            a2[10].x = fmaf(p2.z, xv.x, a2[10].x); a2[10].y = fmaf(p2.z, xv.y, a2[10].y);
            a2[11].x = fmaf(p2.w, xv.x, a2[11].x); a2[11].y = fmaf(p2.w, xv.y, a2[11].y);
            a2[12].x = fmaf(p3.x, xv.x, a2[12].x); a2[12].y = fmaf(p3.x, xv.y, a2[12].y);
            a2[13].x = fmaf(p3.y, xv.x, a2[13].x); a2[13].y = fmaf(p3.y, xv.y, a2[13].y);
            a2[14].x = fmaf(p3.z, xv.x, a2[14].x); a2[14].y = fmaf(p3.z, xv.y, a2[14].y);
            a2[15].x = fmaf(p3.w, xv.x, a2[15].x); a2[15].y = fmaf(p3.w, xv.y, a2[15].y);
        }
        float* pb = part + ((size_t)ss * B + b) * (H * E) + wid * 128 + lane * 2;
#pragma unroll
        for (int h = 0; h < 16; ++h) *(float2*)(pb + (size_t)h * E) = a2[h];
    }
}

// ---------------------------------------------------------------- ctxc: combine chunk partials (online-softmax rescale) + Wv projection
__global__ __launch_bounds__(256) void ctxc_kernel(const float* __restrict__ W,
                                                   const float* __restrict__ bqkv,
                                                   const float* __restrict__ part,
                                                   const float* __restrict__ mstat,
                                                   const float* __restrict__ lstat,
                                                   float* __restrict__ ctx) {
    int cb = blockIdx.x, b = blockIdx.y, t = threadIdx.x;
    int h0 = cb * 4;
    __shared__ float xls[4 * E];  // 16 KB
    __shared__ float fs[4][CH];
    __shared__ float linv[4];
    if (t < 4) {
        int h = h0 + t;
        float mv[CH];
        float mg = -1e30f;
#pragma unroll
        for (int c = 0; c < CH; ++c) {
            mv[c] = mstat[((size_t)c * B + b) * H + h];
            mg = fmaxf(mg, mv[c]);
        }
        float l = 0.f;
#pragma unroll
        for (int c = 0; c < CH; ++c) {
            float fc = __expf(mv[c] - mg);
            fs[t][c] = fc;
            l = fmaf(fc, lstat[((size_t)c * B + b) * H + h], l);
        }
        linv[t] = 1.f / l;
    }
    __syncthreads();
    for (int i = t; i < 4 * E / 4; i += 256) {
        int hl = i >> 8, e4 = i & 255;
        float4 s = make_float4(0.f, 0.f, 0.f, 0.f);
#pragma unroll 4
        for (int c = 0; c < CH; ++c) {
            float fc = fs[hl][c];
            float4 v = ((const float4*)part)[(((size_t)c * B + b) * H + h0 + hl) * (E / 4) + e4];
            s.x = fmaf(fc, v.x, s.x); s.y = fmaf(fc, v.y, s.y);
            s.z = fmaf(fc, v.z, s.z); s.w = fmaf(fc, v.w, s.w);
        }
        float li = linv[hl];
        s.x *= li; s.y *= li; s.z *= li; s.w *= li;
        ((float4*)xls)[i] = s;
    }
    __syncthreads();
    int c = cb * 256 + t;
    int h = c >> 6;
    const float4* wr = (const float4*)(W + ((size_t)(2 * E + c)) * E);
    const float4* xl = (const float4*)(xls + (h - h0) * E);
    float acc = bqkv[2 * E + c];
#pragma unroll 4
    for (int e4 = 0; e4 < E / 4; ++e4) {
        float4 w = wr[e4], xv = xl[e4];
        acc = fmaf(w.x, xv.x, acc); acc = fmaf(w.y, xv.y, acc);
        acc = fmaf(w.z, xv.z, acc); acc = fmaf(w.w, xv.w, acc);
    }
    ctx[(size_t)b * E + c] = acc;
}

// ---------------------------------------------------------------- out[b][o] = ob[o] + Wo[o] . ctx[b]
__global__ __launch_bounds__(256) void outproj_kernel(const float* __restrict__ Wo,
                                                      const float* __restrict__ ob,
                                                      const float* __restrict__ ctx,
                                                      float* __restrict__ outpre) {
    int obk = blockIdx.x, b = blockIdx.y, t = threadIdx.x;
    int o = obk * 256 + t;
    __shared__ float cl[E];  // 4 KB
    const float4* cp = (const float4*)(ctx + (size_t)b * E);
    for (int i = t; i < E / 4; i += 256) ((float4*)cl)[i] = cp[i];
    __syncthreads();
    const float4* wr = (const float4*)(Wo + (size_t)o * E);
    const float4* cl4 = (const float4*)cl;
    float acc = ob[o];
#pragma unroll 4
    for (int e4 = 0; e4 < E / 4; ++e4) {
        float4 w = wr[e4], cv = cl4[e4];
        acc = fmaf(w.x, cv.x, acc); acc = fmaf(w.y, cv.y, acc);
        acc = fmaf(w.z, cv.z, acc); acc = fmaf(w.w, cv.w, acc);
    }
    outpre[(size_t)b * E + o] = acc;
}

// ---------------------------------------------------------------- LayerNorm over E per b
__global__ __launch_bounds__(256) void ln_kernel(const float* __restrict__ outpre,
                                                 const float* __restrict__ g,
                                                 const float* __restrict__ bb,
                                                 float* __restrict__ out) {
    int b = blockIdx.x, t = threadIdx.x, lane = t & 63, wid = t >> 6;
    const float4* row = (const float4*)(outpre + (size_t)b * E);
    float4 v = row[t];
    float s = v.x + v.y + v.z + v.w;
    float sq = v.x * v.x + v.y * v.y + v.z * v.z + v.w * v.w;
    __shared__ float rs[4], rq[4];
#pragma unroll
    for (int off = 32; off > 0; off >>= 1) {
        s += __shfl_down(s, off, 64);
        sq += __shfl_down(sq, off, 64);
    }
    if (lane == 0) { rs[wid] = s; rq[wid] = sq; }
    __syncthreads();
    s = rs[0] + rs[1] + rs[2] + rs[3];
    sq = rq[0] + rq[1] + rq[2] + rq[3];
    float mean = s * (1.f / E);
    float var = sq * (1.f / E) - mean * mean;
    float inv = rsqrtf(var + 1e-5f);
    float4 gv = ((const float4*)g)[t];
    float4 bv = ((const float4*)bb)[t];
    float4 o;
    o.x = (v.x - mean) * inv * gv.x + bv.x;
    o.y = (v.y - mean) * inv * gv.y + bv.y;
    o.z = (v.z - mean) * inv * gv.z + bv.z;
    o.w = (v.w - mean) * inv * gv.w + bv.w;
    ((float4*)(out + (size_t)b * E))[t] = o;
}

extern "C" void kernel_launch(void* const* d_in, const int* in_sizes, int n_in,
                              void* d_out, int out_size, void* d_ws, size_t ws_size,
                              hipStream_t stream) {
    const float* x    = (const float*)d_in[0];
    const int*   mask = (const int*)d_in[1];
    const float* seed = (const float*)d_in[2];
    const float* W    = (const float*)d_in[3];  // (3E, E)
    const float* bqkv = (const float*)d_in[4];  // (3E,)
    const float* Wo   = (const float*)d_in[5];  // (E, E)
    const float* ob   = (const float*)d_in[6];  // (E,)
    const float* g    = (const float*)d_in[7];
    const float* lb   = (const float*)d_in[8];
    float* out = (float*)d_out;

    float* ws = (float*)d_ws;
    float* q      = ws;                           // E
    float* u      = q + E;                        // H*E
    float* part   = u + H * E;                    // CH*B*H*E
    float* mstat  = part + (size_t)CH * BHE;      // CH*B*H
    float* lstat  = mstat + (size_t)CH * B * H;   // CH*B*H
    float* ctx    = lstat + (size_t)CH * B * H;   // B*E
    float* outpre = ctx + (size_t)B * E;          // B*E

    qproj_kernel<<<256, 256, 0, stream>>>(W, bqkv, seed, q);
    uproj_kernel<<<dim3(E / 256, H), 256, 0, stream>>>(W, q, u);
    fused_kernel<<<dim3(CH, B), 512, 0, stream>>>(x, mask, u, part, mstat, lstat);
    ctxc_kernel<<<dim3(E / 256, B), 256, 0, stream>>>(W, bqkv, part, mstat, lstat, ctx);
    outproj_kernel<<<dim3(E / 256, B), 256, 0, stream>>>(Wo, ob, ctx, outpre);
    ln_kernel<<<B, 256, 0, stream>>>(outpre, g, lb, out);
}

// Round 10
// 131.287 us; speedup vs baseline: 5.7650x; 1.1334x over previous
//
#include <hip/hip_runtime.h>
#include <hip/hip_bf16.h>
#include <math.h>

#define E 1024
#define H 16
#define HD 64
#define B 32
#define S 2048
#define CH 16           // 128-token chunks per batch row
#define CTOK (S / CH)   // 128 tokens per chunk
#define SUB 32          // tokens per sub-tile
#define NSUB (CTOK / SUB)
#define BHE (B * H * E)

typedef __attribute__((ext_vector_type(8))) short short8;
typedef __attribute__((ext_vector_type(4))) float f32x4;

__device__ __forceinline__ short f2bf(float f) {
    union { __hip_bfloat16 h; short s; } u;
    u.h = __float2bfloat16(f);
    return u.s;
}

// ---------------------------------------------------------------- q = Wq @ seed + bq
__global__ __launch_bounds__(256) void qproj_kernel(const float* __restrict__ W,
                                                    const float* __restrict__ bqkv,
                                                    const float* __restrict__ seed,
                                                    float* __restrict__ q) {
    int gw = (blockIdx.x * 256 + threadIdx.x) >> 6;  // e index
    int lane = threadIdx.x & 63;
    if (gw >= E) return;
    const float4* row = (const float4*)(W + (size_t)gw * E);
    const float4* sd = (const float4*)seed;
    float acc = 0.f;
#pragma unroll
    for (int k = 0; k < 4; ++k) {
        float4 w4 = row[k * 64 + lane];
        float4 s4 = sd[k * 64 + lane];
        acc = fmaf(w4.x, s4.x, acc); acc = fmaf(w4.y, s4.y, acc);
        acc = fmaf(w4.z, s4.z, acc); acc = fmaf(w4.w, s4.w, acc);
    }
#pragma unroll
    for (int off = 32; off > 0; off >>= 1) acc += __shfl_down(acc, off, 64);
    if (lane == 0) q[gw] = acc + bqkv[gw];
}

// ---------------------------------------------------------------- ubf[h][e] = bf16( scale * sum_d q[h*64+d] * Wk[h*64+d][e] )
__global__ __launch_bounds__(256) void uproj_kernel(const float* __restrict__ W,
                                                    const float* __restrict__ q,
                                                    short* __restrict__ ubf) {
    int h = blockIdx.y;
    int e = blockIdx.x * 256 + threadIdx.x;
    __shared__ float qs[HD];
    if (threadIdx.x < HD) qs[threadIdx.x] = q[h * HD + threadIdx.x];
    __syncthreads();
    const float* Wk = W + ((size_t)(E + h * HD)) * E + e;
    float acc = 0.f;
#pragma unroll 8
    for (int d = 0; d < HD; ++d) acc = fmaf(qs[d], Wk[(size_t)d * E], acc);
    ubf[(size_t)h * E + e] = f2bf(acc * 0.125f);  // 1/sqrt(64)
}

// ---------------------------------------------------------------- fused single-pass flash kernel per (chunk, b)
// 4 sub-tiles of 32 tokens. Per sub-tile:
//   stage:  x[32][1024] -> bf16 -> swizzled LDS (byte ^= (tok&7)<<4), mask-skipped (x read ONCE from HBM)
//   scores: 8 waves = 2 token-tiles x 4 K-quarters, mfma_f32_16x16x32_bf16,
//           A from LDS (b128, uniform 8-way = floor), B = ubf from global (L2-broadcast).
//           Operand/C mapping identical to the R9-verified kernel.
//   online softmax: running m,l per head; rescale a2 by exp(m_old-m_new).
//   pool:   a2[16] float2 per thread (e = tid*2), x from LDS bf16, p from LDS.
// Output: unnormalized part + (m,l) stats — ctxc combine unchanged.
__global__ __launch_bounds__(512, 4) void fused_kernel(const float* __restrict__ x,
                                                       const int* __restrict__ mask,
                                                       const short* __restrict__ ubf,
                                                       float* __restrict__ part,
                                                       float* __restrict__ mstat,
                                                       float* __restrict__ lstat) {
    int ss = blockIdx.x, b = blockIdx.y;
    __shared__ short xB[SUB * E];          // 64 KB bf16 [tok][e], XOR-swizzled
    __shared__ float scp[8 * 64 * 4];      // 8 KB cross-kq partials [wave][lane][reg]
    __shared__ float pcur[SUB * H];        // 2 KB  p of current sub-tile [tok][h]
    __shared__ int   mk[CTOK];             // 512 B
    __shared__ float mrun[H], lrun[H], rfac[H];
    __shared__ float wred[8][16];

    int tid = threadIdx.x, lane = tid & 63, wid = tid >> 6;

    if (tid < H) { mrun[tid] = -1e30f; lrun[tid] = 0.f; }
    for (int i = tid; i < CTOK; i += 512) mk[i] = mask[(size_t)b * S + ss * CTOK + i];

    float2 a2[16];
#pragma unroll
    for (int h = 0; h < 16; ++h) a2[h] = make_float2(0.f, 0.f);

    __syncthreads();

    for (int sub = 0; sub < NSUB; ++sub) {
        int t0 = sub * SUB;

        // ---- stage x -> xB ----
        {
            int tok = tid >> 4;        // 0..31
            int es  = tid & 15;
            const float* xr = x + ((size_t)b * S + ss * CTOK + t0 + tok) * E;
            bool live = mk[t0 + tok] != 0;
#pragma unroll
            for (int i = 0; i < 8; ++i) {
                int e0 = (es + i * 16) * 8;
                if (live) {
                    float4 lo = *(const float4*)(xr + e0);
                    float4 hi = *(const float4*)(xr + e0 + 4);
                    short8 v;
                    v[0] = f2bf(lo.x); v[1] = f2bf(lo.y); v[2] = f2bf(lo.z); v[3] = f2bf(lo.w);
                    v[4] = f2bf(hi.x); v[5] = f2bf(hi.y); v[6] = f2bf(hi.z); v[7] = f2bf(hi.w);
                    int byte = (tok * 2048 + e0 * 2) ^ ((tok & 7) << 4);
                    *(short8*)((char*)xB + byte) = v;
                }
            }
        }
        __syncthreads();

        // ---- MFMA scores: wave (tw = wid&1, kq = wid>>1) ----
        {
            int tw = wid & 1, kq = wid >> 1;
            int tr = lane & 15, kg = lane >> 4;
            int tok = tw * 16 + tr;
            f32x4 acc = {0.f, 0.f, 0.f, 0.f};
            const short* ub = ubf + (size_t)tr * E;
#pragma unroll
            for (int st = 0; st < 8; ++st) {
                int e0 = kq * 256 + st * 32 + kg * 8;
                int byte = (tok * 2048 + e0 * 2) ^ ((tok & 7) << 4);
                short8 a = *(const short8*)((char*)xB + byte);
                short8 bv = *(const short8*)(ub + e0);
                acc = __builtin_amdgcn_mfma_f32_16x16x32_bf16(a, bv, acc, 0, 0, 0);
            }
            *(f32x4*)&scp[(wid * 64 + lane) * 4] = acc;
        }
        __syncthreads();

        // ---- reduce over kq + online softmax update ----
        {
            int tok = tid >> 4, h = tid & 15;   // local token 0..31
            int tw = tok >> 4, r = tok & 3, kg2 = (tok & 15) >> 2;
            float s = 0.f;
#pragma unroll
            for (int kq = 0; kq < 4; ++kq)
                s += scp[((kq * 2 + tw) * 64 + kg2 * 16 + h) * 4 + r];
            bool live = mk[t0 + tok] != 0;
            float sv = live ? s : -1e30f;
            float mx = sv;
            mx = fmaxf(mx, __shfl_xor(mx, 16, 64));
            mx = fmaxf(mx, __shfl_xor(mx, 32, 64));
            if (lane < 16) wred[wid][lane] = mx;
            __syncthreads();
            if (tid < 16) {
                float mt = wred[0][tid];
#pragma unroll
                for (int w = 1; w < 8; ++w) mt = fmaxf(mt, wred[w][tid]);
                float mo = mrun[tid];
                float mn = fmaxf(mo, mt);
                rfac[tid] = __expf(mo - mn);
                mrun[tid] = mn;
            }
            __syncthreads();
            float p = live ? __expf(s - mrun[h]) : 0.f;
            pcur[tok * 16 + h] = p;
            float ps = p;
            ps += __shfl_xor(ps, 16, 64);
            ps += __shfl_xor(ps, 32, 64);
            if (lane < 16) wred[wid][lane] = ps;
            __syncthreads();
            if (tid < 16) {
                float lt = 0.f;
#pragma unroll
                for (int w = 0; w < 8; ++w) lt += wred[w][tid];
                lrun[tid] = lrun[tid] * rfac[tid] + lt;
            }
        }
        __syncthreads();

        // ---- pool: rescale + accumulate from LDS ----
        {
#pragma unroll
            for (int h = 0; h < 16; ++h) {
                float r = rfac[h];
                a2[h].x *= r; a2[h].y *= r;
            }
            int ebyte = tid * 4;  // 2 bf16 = 4 bytes at e = tid*2
            for (int tok = 0; tok < SUB; ++tok) {
                if (!mk[t0 + tok]) continue;
                int byte = (tok * 2048 + ebyte) ^ ((tok & 7) << 4);
                unsigned xv2 = *(const unsigned*)((char*)xB + byte);
                float xe0 = __uint_as_float(xv2 << 16);
                float xe1 = __uint_as_float(xv2 & 0xffff0000u);
                const float4* pr = (const float4*)&pcur[tok * 16];
                float4 p0 = pr[0], p1 = pr[1], p2 = pr[2], p3 = pr[3];
                a2[0].x = fmaf(p0.x, xe0, a2[0].x);   a2[0].y = fmaf(p0.x, xe1, a2[0].y);
                a2[1].x = fmaf(p0.y, xe0, a2[1].x);   a2[1].y = fmaf(p0.y, xe1, a2[1].y);
                a2[2].x = fmaf(p0.z, xe0, a2[2].x);   a2[2].y = fmaf(p0.z, xe1, a2[2].y);
                a2[3].x = fmaf(p0.w, xe0, a2[3].x);   a2[3].y = fmaf(p0.w, xe1, a2[3].y);
                a2[4].x = fmaf(p1.x, xe0, a2[4].x);   a2[4].y = fmaf(p1.x, xe1, a2[4].y);
                a2[5].x = fmaf(p1.y, xe0, a2[5].x);   a2[5].y = fmaf(p1.y, xe1, a2[5].y);
                a2[6].x = fmaf(p1.z, xe0, a2[6].x);   a2[6].y = fmaf(p1.z, xe1, a2[6].y);
                a2[7].x = fmaf(p1.w, xe0, a2[7].x);   a2[7].y = fmaf(p1.w, xe1, a2[7].y);
                a2[8].x = fmaf(p2.x, xe0, a2[8].x);   a2[8].y = fmaf(p2.x, xe1, a2[8].y);
                a2[9].x = fmaf(p2.y, xe0, a2[9].x);   a2[9].y = fmaf(p2.y, xe1, a2[9].y);
                a2[10].x = fmaf(p2.z, xe0, a2[10].x); a2[10].y = fmaf(p2.z, xe1, a2[10].y);
                a2[11].x = fmaf(p2.w, xe0, a2[11].x); a2[11].y = fmaf(p2.w, xe1, a2[11].y);
                a2[12].x = fmaf(p3.x, xe0, a2[12].x); a2[12].y = fmaf(p3.x, xe1, a2[12].y);
                a2[13].x = fmaf(p3.y, xe0, a2[13].x); a2[13].y = fmaf(p3.y, xe1, a2[13].y);
                a2[14].x = fmaf(p3.z, xe0, a2[14].x); a2[14].y = fmaf(p3.z, xe1, a2[14].y);
                a2[15].x = fmaf(p3.w, xe0, a2[15].x); a2[15].y = fmaf(p3.w, xe1, a2[15].y);
            }
        }
        __syncthreads();  // protect xB before next stage
    }

    // ---- write unnormalized partial + stats ----
    float* pb = part + ((size_t)ss * B + b) * (H * E) + tid * 2;
#pragma unroll
    for (int h = 0; h < 16; ++h) *(float2*)(pb + (size_t)h * E) = a2[h];
    if (tid < 16) {
        mstat[((size_t)ss * B + b) * H + tid] = mrun[tid];
        lstat[((size_t)ss * B + b) * H + tid] = lrun[tid];
    }
}

// ---------------------------------------------------------------- ctxc: combine chunk partials (online-softmax rescale) + Wv projection
__global__ __launch_bounds__(256) void ctxc_kernel(const float* __restrict__ W,
                                                   const float* __restrict__ bqkv,
                                                   const float* __restrict__ part,
                                                   const float* __restrict__ mstat,
                                                   const float* __restrict__ lstat,
                                                   float* __restrict__ ctx) {
    int cb = blockIdx.x, b = blockIdx.y, t = threadIdx.x;
    int h0 = cb * 4;
    __shared__ float xls[4 * E];  // 16 KB
    __shared__ float fs[4][CH];
    __shared__ float linv[4];
    if (t < 4) {
        int h = h0 + t;
        float mv[CH];
        float mg = -1e30f;
#pragma unroll
        for (int c = 0; c < CH; ++c) {
            mv[c] = mstat[((size_t)c * B + b) * H + h];
            mg = fmaxf(mg, mv[c]);
        }
        float l = 0.f;
#pragma unroll
        for (int c = 0; c < CH; ++c) {
            float fc = __expf(mv[c] - mg);
            fs[t][c] = fc;
            l = fmaf(fc, lstat[((size_t)c * B + b) * H + h], l);
        }
        linv[t] = 1.f / l;
    }
    __syncthreads();
    for (int i = t; i < 4 * E / 4; i += 256) {
        int hl = i >> 8, e4 = i & 255;
        float4 s = make_float4(0.f, 0.f, 0.f, 0.f);
#pragma unroll 4
        for (int c = 0; c < CH; ++c) {
            float fc = fs[hl][c];
            float4 v = ((const float4*)part)[(((size_t)c * B + b) * H + h0 + hl) * (E / 4) + e4];
            s.x = fmaf(fc, v.x, s.x); s.y = fmaf(fc, v.y, s.y);
            s.z = fmaf(fc, v.z, s.z); s.w = fmaf(fc, v.w, s.w);
        }
        float li = linv[hl];
        s.x *= li; s.y *= li; s.z *= li; s.w *= li;
        ((float4*)xls)[i] = s;
    }
    __syncthreads();
    int c = cb * 256 + t;
    int h = c >> 6;
    const float4* wr = (const float4*)(W + ((size_t)(2 * E + c)) * E);
    const float4* xl = (const float4*)(xls + (h - h0) * E);
    float acc = bqkv[2 * E + c];
#pragma unroll 4
    for (int e4 = 0; e4 < E / 4; ++e4) {
        float4 w = wr[e4], xv = xl[e4];
        acc = fmaf(w.x, xv.x, acc); acc = fmaf(w.y, xv.y, acc);
        acc = fmaf(w.z, xv.z, acc); acc = fmaf(w.w, xv.w, acc);
    }
    ctx[(size_t)b * E + c] = acc;
}

// ---------------------------------------------------------------- out[b][o] = ob[o] + Wo[o] . ctx[b]
__global__ __launch_bounds__(256) void outproj_kernel(const float* __restrict__ Wo,
                                                      const float* __restrict__ ob,
                                                      const float* __restrict__ ctx,
                                                      float* __restrict__ outpre) {
    int obk = blockIdx.x, b = blockIdx.y, t = threadIdx.x;
    int o = obk * 256 + t;
    __shared__ float cl[E];  // 4 KB
    const float4* cp = (const float4*)(ctx + (size_t)b * E);
    for (int i = t; i < E / 4; i += 256) ((float4*)cl)[i] = cp[i];
    __syncthreads();
    const float4* wr = (const float4*)(Wo + (size_t)o * E);
    const float4* cl4 = (const float4*)cl;
    float acc = ob[o];
#pragma unroll 4
    for (int e4 = 0; e4 < E / 4; ++e4) {
        float4 w = wr[e4], cv = cl4[e4];
        acc = fmaf(w.x, cv.x, acc); acc = fmaf(w.y, cv.y, acc);
        acc = fmaf(w.z, cv.z, acc); acc = fmaf(w.w, cv.w, acc);
    }
    outpre[(size_t)b * E + o] = acc;
}

// ---------------------------------------------------------------- LayerNorm over E per b
__global__ __launch_bounds__(256) void ln_kernel(const float* __restrict__ outpre,
                                                 const float* __restrict__ g,
                                                 const float* __restrict__ bb,
                                                 float* __restrict__ out) {
    int b = blockIdx.x, t = threadIdx.x, lane = t & 63, wid = t >> 6;
    const float4* row = (const float4*)(outpre + (size_t)b * E);
    float4 v = row[t];
    float s = v.x + v.y + v.z + v.w;
    float sq = v.x * v.x + v.y * v.y + v.z * v.z + v.w * v.w;
    __shared__ float rs[4], rq[4];
#pragma unroll
    for (int off = 32; off > 0; off >>= 1) {
        s += __shfl_down(s, off, 64);
        sq += __shfl_down(sq, off, 64);
    }
    if (lane == 0) { rs[wid] = s; rq[wid] = sq; }
    __syncthreads();
    s = rs[0] + rs[1] + rs[2] + rs[3];
    sq = rq[0] + rq[1] + rq[2] + rq[3];
    float mean = s * (1.f / E);
    float var = sq * (1.f / E) - mean * mean;
    float inv = rsqrtf(var + 1e-5f);
    float4 gv = ((const float4*)g)[t];
    float4 bv = ((const float4*)bb)[t];
    float4 o;
    o.x = (v.x - mean) * inv * gv.x + bv.x;
    o.y = (v.y - mean) * inv * gv.y + bv.y;
    o.z = (v.z - mean) * inv * gv.z + bv.z;
    o.w = (v.w - mean) * inv * gv.w + bv.w;
    ((float4*)(out + (size_t)b * E))[t] = o;
}

extern "C" void kernel_launch(void* const* d_in, const int* in_sizes, int n_in,
                              void* d_out, int out_size, void* d_ws, size_t ws_size,
                              hipStream_t stream) {
    const float* x    = (const float*)d_in[0];
    const int*   mask = (const int*)d_in[1];
    const float* seed = (const float*)d_in[2];
    const float* W    = (const float*)d_in[3];  // (3E, E)
    const float* bqkv = (const float*)d_in[4];  // (3E,)
    const float* Wo   = (const float*)d_in[5];  // (E, E)
    const float* ob   = (const float*)d_in[6];  // (E,)
    const float* g    = (const float*)d_in[7];
    const float* lb   = (const float*)d_in[8];
    float* out = (float*)d_out;

    float* ws = (float*)d_ws;
    float* q      = ws;                           // E
    float* part   = q + E;                        // CH*B*H*E
    float* mstat  = part + (size_t)CH * BHE;      // CH*B*H
    float* lstat  = mstat + (size_t)CH * B * H;   // CH*B*H
    short* ubf    = (short*)(lstat + (size_t)CH * B * H);  // H*E bf16
    float* ctx    = (float*)(ubf + (size_t)H * E);         // B*E
    float* outpre = ctx + (size_t)B * E;          // B*E

    qproj_kernel<<<256, 256, 0, stream>>>(W, bqkv, seed, q);
    uproj_kernel<<<dim3(E / 256, H), 256, 0, stream>>>(W, q, ubf);
    fused_kernel<<<dim3(CH, B), 512, 0, stream>>>(x, mask, ubf, part, mstat, lstat);
    ctxc_kernel<<<dim3(E / 256, B), 256, 0, stream>>>(W, bqkv, part, mstat, lstat, ctx);
    outproj_kernel<<<dim3(E / 256, B), 256, 0, stream>>>(Wo, ob, ctx, outpre);
    ln_kernel<<<B, 256, 0, stream>>>(outpre, g, lb, out);
}